// Round 24
// baseline (1382.438 us; speedup 1.0000x reference)
//
#include <hip/hip_runtime.h>

#define B_   32
#define L_   796
#define D_   512
#define H_   8
#define HD_  64
#define FF_  2048
#define CS_  16
#define STR_ 13
#define NC_  61
#define NQT_ 13
#define MC_  976            // NC_*CS_ rows per batch (clip path)
#define QKVS 1536           // fused QKV row stride
#define QS   (0.125f * 1.44269504f)   // 1/sqrt(64) * log2(e)  -> exp2 softmax

typedef __attribute__((ext_vector_type(8))) short short8;
typedef __attribute__((ext_vector_type(4))) short short4v;
typedef __attribute__((ext_vector_type(4))) float f32x4;

__device__ __forceinline__ unsigned short f2bf(float x) {
    unsigned u = __float_as_uint(x);
    unsigned r = u + 0x7FFFu + ((u >> 16) & 1u);   // RNE
    return (unsigned short)(r >> 16);
}
__device__ __forceinline__ float bf2f(unsigned short h) {
    return __uint_as_float(((unsigned)h) << 16);
}
__device__ __forceinline__ float ex2(float x) {      // native v_exp_f32 (2^x)
    return __builtin_amdgcn_exp2f(x);
}
__device__ __forceinline__ void gload16(const unsigned short* g, unsigned short* l) {
    __builtin_amdgcn_global_load_lds(
        (const __attribute__((address_space(1))) void*)g,
        (__attribute__((address_space(3))) void*)l, 16, 0, 0);
}

// ---------------------------------------------------------------------------
// LayerNorm D=512, f32 in -> bf16 out.
// gather=0: direct rows; gather=1: x_rec remap; gather=2: clip build from x.
// ---------------------------------------------------------------------------
__global__ __launch_bounds__(256) void k_ln(const float* __restrict__ in,
                                            unsigned short* __restrict__ out,
                                            const float* __restrict__ gamma,
                                            const float* __restrict__ beta,
                                            int rows_per_batch, int gstride, int gather)
{
    __shared__ float red[8];
    long long row = blockIdx.x;
    int tid = threadIdx.x;
    int b;
    float v0, v1;
    if (gather == 2) {
        b = (int)(row / MC_);
        int rr = (int)(row % MC_);
        int n = rr >> 4, c = rr & 15;
        long long xb = (long long)b * L_ * D_;
        int d0 = tid, st0, sd0;
        if (d0 < 128) { st0 = n * STR_ + c; sd0 = d0; }
        else { int j = d0 - 128; st0 = n * STR_ + (j & 15); sd0 = 128 + ((j >> 4) << 4) + c; }
        v0 = in[xb + (long long)st0 * D_ + sd0];
        int j1 = tid + 128;                 // (tid+256)-128
        int st1 = n * STR_ + (j1 & 15), sd1 = 128 + ((j1 >> 4) << 4) + c;
        v1 = in[xb + (long long)st1 * D_ + sd1];
    } else {
        long long srow = row;
        if (gather == 1) {
            int p = (int)(row % L_);
            b = (int)(row / L_);
            int ci = p / STR_; if (ci > NC_ - 1) ci = NC_ - 1;
            srow = ((long long)b * NC_ + ci) * CS_ + (p - ci * STR_);
        } else {
            b = (int)(row / rows_per_batch);
        }
        const float* xr = in + srow * D_;
        v0 = xr[tid]; v1 = xr[tid + 256];
    }
    float s = v0 + v1;
#pragma unroll
    for (int off = 1; off < 64; off <<= 1) s += __shfl_xor(s, off);
    if ((tid & 63) == 0) red[tid >> 6] = s;
    __syncthreads();
    float mean = (red[0] + red[1] + red[2] + red[3]) * (1.0f / 512.0f);
    float d0 = v0 - mean, d1 = v1 - mean;
    float vv = d0 * d0 + d1 * d1;
#pragma unroll
    for (int off = 1; off < 64; off <<= 1) vv += __shfl_xor(vv, off);
    if ((tid & 63) == 0) red[4 + (tid >> 6)] = vv;
    __syncthreads();
    float var = (red[4] + red[5] + red[6] + red[7]) * (1.0f / 512.0f);
    float rstd = rsqrtf(var + 1e-6f);
    const float* g  = gamma + (long long)b * gstride;
    const float* bt = beta  + (long long)b * gstride;
    unsigned short* o = out + row * D_;
    o[tid]       = f2bf(d0 * rstd * g[tid]       + bt[tid]);
    o[tid + 256] = f2bf(d1 * rstd * g[tid + 256] + bt[tid + 256]);
}

// ---------------------------------------------------------------------------
// Weight transpose+convert: W f32 [K x N] (row stride rowStride) -> T bf16
// [N][K] (row stride tStride). grid (N/32, K/32, G).
// ---------------------------------------------------------------------------
__global__ __launch_bounds__(256) void k_wt(const float* __restrict__ W,
                                            unsigned short* __restrict__ T,
                                            int rowStride, int tStride,
                                            long long sWb, long long sTb)
{
    __shared__ float t[32][33];
    int z = blockIdx.z;
    const float* Wz = W + (long long)z * sWb;
    unsigned short* Tz = T + (long long)z * sTb;
    int n0 = blockIdx.x << 5, k0 = blockIdx.y << 5;
    int tx = threadIdx.x & 31, ty = threadIdx.x >> 5;
#pragma unroll
    for (int i = 0; i < 4; i++) {
        int k = ty + (i << 3);
        t[k][tx] = Wz[(long long)(k0 + k) * rowStride + n0 + tx];
    }
    __syncthreads();
#pragma unroll
    for (int i = 0; i < 4; i++) {
        int n = ty + (i << 3);
        Tz[(long long)(n0 + n) * tStride + k0 + tx] = f2bf(t[tx][n]);
    }
}

// Stacked transpose of up to 4 square 512x512 tensors x nb batches.
// z = tensor*nb + batch. dst: [batch][tensor*512 + n][512].
__global__ __launch_bounds__(256) void k_wt_stack(const float* __restrict__ Wa,
                                                  const float* __restrict__ Wb,
                                                  const float* __restrict__ Wc,
                                                  const float* __restrict__ Wd,
                                                  unsigned short* __restrict__ T,
                                                  int nb, int ntens, long long sWb)
{
    __shared__ float t[32][33];
    int z = blockIdx.z;
    int tt = z / nb, b = z % nb;
    const float* Wz = (tt == 0 ? Wa : tt == 1 ? Wb : tt == 2 ? Wc : Wd)
                      + (long long)b * sWb;
    unsigned short* Tz = T + ((long long)b * ntens + tt) * (512 * 512);
    int n0 = blockIdx.x << 5, k0 = blockIdx.y << 5;
    int tx = threadIdx.x & 31, ty = threadIdx.x >> 5;
#pragma unroll
    for (int i = 0; i < 4; i++) {
        int k = ty + (i << 3);
        t[k][tx] = Wz[(long long)(k0 + k) * 512 + n0 + tx];
    }
    __syncthreads();
#pragma unroll
    for (int i = 0; i < 4; i++) {
        int n = ty + (i << 3);
        Tz[(long long)(n0 + n) * 512 + k0 + tx] = f2bf(t[tx][n]);
    }
}

// ---------------------------------------------------------------------------
// bf16 MFMA GEMM — counted-vmcnt pipeline (round-12 skeleton), BK=32,
// 512 thr / 8 waves (2M x 4N, each wave 64x32 out) — round-21/23 proven best.
// NOTE: no min-waves clause (r22: forcing 8 waves/EU spilled VGPR 80->32).
// Swizzle key (r>>1)&3 (conflict-free, r20-verified: 0 conflicts).
// ---------------------------------------------------------------------------
__global__ __launch_bounds__(512) void k_gemm_mfma(
    const unsigned short* __restrict__ A, const unsigned short* __restrict__ WT,
    const float* __restrict__ b0p, const float* __restrict__ b1p,
    const float* __restrict__ b2p,
    const float* res, const float* __restrict__ xg, void* Cout,
    int M, int N, int K, int ldwk, int NX, int NYd, int mode,
    long long sAb, long long sWb, long long sBb, long long sRb, long long sCb,
    float alpha, float alpha1, int relu, int biasmode, int resmode, int outbf16)
{
    __shared__ unsigned short lds[16384];      // 32 KB: 2 x (A 8KB + W 8KB)
    int tid = threadIdx.x;

    // ---- XCD-aware decode ----
    int bid = blockIdx.x;
    int xcd = bid & 7, inner = bid >> 3;
    int x = inner % NX, t = inner / NX;
    int y, z;
    if (mode == 0) { y = t % NYd; z = (t / NYd) * 8 + xcd; }
    else           { y = t * 8 + xcd; z = 0; }
    int row0 = y << 7, col0 = x << 7;
    if (row0 >= M) return;                 // padded row-tile (mode 1)

    const unsigned short* Ab = A + z * sAb;
    const unsigned short* Wb = WT + z * sWb;

    int w = tid >> 6, lane = tid & 63;
    int wr = (w >> 2) << 6;                // 0 / 64
    int wc = (w & 3) << 5;                 // 0 / 32 / 64 / 96
    int l15 = lane & 15, lg = lane >> 4;   // lg in 0..3 = K-slot of 32
    int lrow4 = lane >> 2, lslot = lane & 3;   // staging: 16 rows x 4 slots/wave

    f32x4 acc[4][2];
#pragma unroll
    for (int i = 0; i < 4; i++)
#pragma unroll
        for (int j = 0; j < 2; j++) acc[i][j] = (f32x4)0.f;

    const int nt = K >> 5;                     // BK = 32
    int srow = (w << 4) + lrow4;               // staging row (wave w: rows w*16..+15)
    int skey = (srow >> 1) & 3;

    // ---- prologue: stage tile 0 -> buf0, tile 1 -> buf1 ----
#pragma unroll
    for (int pt = 0; pt < 2; ++pt) {
        int k0 = pt << 5;
        unsigned short* sA = lds + (pt << 13);
        unsigned short* sW = sA + 4096;
        gload16(Ab + (long long)(row0 + srow) * K + k0 + ((lslot ^ skey) << 3),
                sA + ((w << 4) << 5));
        gload16(Wb + (long long)(col0 + srow) * ldwk + k0 + ((lslot ^ skey) << 3),
                sW + ((w << 4) << 5));
    }

    for (int kt = 0; kt < nt; ++kt) {
        // (1) counted wait: tile kt's 2 loads landed; tile kt+1's stay in flight
        if (kt + 1 < nt) asm volatile("s_waitcnt vmcnt(2)" ::: "memory");
        else             asm volatile("s_waitcnt vmcnt(0)" ::: "memory");
        __builtin_amdgcn_s_barrier();      // all waves' tile-kt loads landed

        unsigned short* lA = lds + ((kt & 1) << 13);
        unsigned short* lW = lA + 4096;

        // (2) ds_read fragments of current buffer (slot = lg ^ key)
        short8 af[4], bfr[2];
#pragma unroll
        for (int mf = 0; mf < 4; mf++) {
            int r = wr + (mf << 4) + l15;
            af[mf] = *(const short8*)(lA + (r << 5) + ((lg ^ ((r >> 1) & 3)) << 3));
        }
#pragma unroll
        for (int nf = 0; nf < 2; nf++) {
            int r = wc + (nf << 4) + l15;
            bfr[nf] = *(const short8*)(lW + (r << 5) + ((lg ^ ((r >> 1) & 3)) << 3));
        }

        // (3) own reads retired -> all-waves barrier (raw: no vmcnt drain!)
        asm volatile("s_waitcnt lgkmcnt(0)" ::: "memory");
        __builtin_amdgcn_s_barrier();

        // (4) stage tile kt+2 into the buffer just consumed (now safe)
        if (kt + 2 < nt) {
            int k0 = (kt + 2) << 5;
            gload16(Ab + (long long)(row0 + srow) * K + k0 + ((lslot ^ skey) << 3),
                    lA + ((w << 4) << 5));
            gload16(Wb + (long long)(col0 + srow) * ldwk + k0 + ((lslot ^ skey) << 3),
                    lW + ((w << 4) << 5));
        }

        // (5) register-only MFMA cluster
        __builtin_amdgcn_s_setprio(1);
#pragma unroll
        for (int mf = 0; mf < 4; mf++)
#pragma unroll
            for (int nf = 0; nf < 2; nf++)
                acc[mf][nf] = __builtin_amdgcn_mfma_f32_16x16x32_bf16(
                    af[mf], bfr[nf], acc[mf][nf], 0, 0, 0);
        __builtin_amdgcn_s_setprio(0);
    }

#pragma unroll
    for (int mf = 0; mf < 4; mf++) {
#pragma unroll
        for (int reg = 0; reg < 4; reg++) {
            int gr = row0 + wr + (mf << 4) + (lg << 2) + reg;
            if (gr >= M) continue;
#pragma unroll
            for (int nf = 0; nf < 2; nf++) {
                int gc = col0 + wc + (nf << 4) + l15;
                float v = acc[mf][nf][reg];
                if (biasmode == 1) v += b0p[z * sBb + gc];
                else if (biasmode == 3) {
                    const float* bp = gc < 512 ? b0p : (gc < 1024 ? b1p : b2p);
                    v += bp[z * sBb + (gc & 511)];
                }
                v *= (gc < 512) ? alpha : alpha1;
                if (relu) v = fmaxf(v, 0.f);
                if (resmode == 1) {
                    v += res[z * sRb + (long long)gr * N + gc];
                } else if (resmode == 2) {
                    int n = gr >> 4, c = gr & 15;
                    int st, sd;
                    if (gc < 128) { st = n * STR_ + c; sd = gc; }
                    else {
                        int jj = gc - 128;
                        st = n * STR_ + (jj & 15);
                        sd = 128 + ((jj >> 4) << 4) + c;
                    }
                    v += xg[((long long)z * L_ + st) * D_ + sd];
                }
                long long co = z * sCb + (long long)gr * N + gc;
                if (outbf16) ((unsigned short*)Cout)[co] = f2bf(v);
                else         ((float*)Cout)[co] = v;
            }
        }
    }
}

// ---------------------------------------------------------------------------
// Clip attention on fused QKV (stride QKVS, offsets 0/512/1024), exp2 softmax.
// Vectorized: one short4 load per tensor per thread; packed ushort4 ctx store.
// ---------------------------------------------------------------------------
__global__ __launch_bounds__(256) void k_clip_attn(const unsigned short* __restrict__ qkv,
                                                   unsigned short* __restrict__ ctx)
{
    __shared__ float qs[CS_][65], ks[CS_][65], vs[CS_][65], ps[CS_][17];
    int id = blockIdx.x;
    int h = id & (H_ - 1);
    int n = (id / H_) % NC_;
    int b = id / (H_ * NC_);
    long long base = (((long long)b * NC_ + n) * CS_) * QKVS + h * HD_;
    int tid = threadIdx.x;
    {
        int e = tid << 2;                  // 4 contiguous elems (same row)
        int r = e >> 6, c = e & 63;
        long long ro = base + (long long)r * QKVS + c;
        short4v qv = *(const short4v*)(qkv + ro);
        short4v kv = *(const short4v*)(qkv + ro + 512);
        short4v vv = *(const short4v*)(qkv + ro + 1024);
#pragma unroll
        for (int j = 0; j < 4; j++) {
            qs[r][c + j] = bf2f((unsigned short)qv[j]);
            ks[r][c + j] = bf2f((unsigned short)kv[j]);
            vs[r][c + j] = bf2f((unsigned short)vv[j]);
        }
    }
    __syncthreads();
    int qr = tid >> 4, kc = tid & 15;
    float s = 0.f;
#pragma unroll
    for (int d = 0; d < HD_; d++) s += qs[qr][d] * ks[kc][d];
    float m = s;
#pragma unroll
    for (int off = 1; off < 16; off <<= 1) m = fmaxf(m, __shfl_xor(m, off));
    float e = ex2(s - m);
    float sum = e;
#pragma unroll
    for (int off = 1; off < 16; off <<= 1) sum += __shfl_xor(sum, off);
    ps[qr][kc] = e / sum;
    __syncthreads();
    int dg = (tid & 15) * 4;
    float o0 = 0, o1 = 0, o2 = 0, o3 = 0;
#pragma unroll
    for (int kk = 0; kk < CS_; kk++) {
        float pp = ps[qr][kk];
        o0 += pp * vs[kk][dg + 0];
        o1 += pp * vs[kk][dg + 1];
        o2 += pp * vs[kk][dg + 2];
        o3 += pp * vs[kk][dg + 3];
    }
    long long ob = ((((long long)b * NC_ + n) * CS_) + qr) * D_ + h * HD_ + dg;
    short4v ov;
    ov[0] = (short)f2bf(o0); ov[1] = (short)f2bf(o1);
    ov[2] = (short)f2bf(o2); ov[3] = (short)f2bf(o3);
    *(short4v*)(ctx + ob) = ov;
}

// ---------------------------------------------------------------------------
// Global flash attention (MFMA, exp2 softmax) on fused QKV buffer.
// Block = (b, h, 64-row q-tile), 4 waves x 16 q-rows. LDS 24KB (Q aliased as
// P scratch after qf load + lgkmcnt(0)). Mask only last kv-tile. Defer-max
// (T13, THR=8 log2). l computed via MFMA against an all-ones B fragment
// (same bf16 P as PV -> consistent normalization; removes 16 add + 16
// shfl_xor per tile). XCD swizzle: h = bid&7.
// ---------------------------------------------------------------------------
__global__ __launch_bounds__(256) void k_flash_mfma(
    const unsigned short* __restrict__ qkv,
    unsigned short* __restrict__ out)
{
    __shared__ unsigned short sh[12288];   // 24KB: [0,8K)=Q then P; K; V
    unsigned short* lQ = sh;               // 64x64 Q tile (dead after qf load)
    unsigned short* lK = sh + 4096;
    unsigned short* lV = sh + 8192;
    int bid = blockIdx.x;
    int h  = bid & 7;
    int inner = bid >> 3;
    int qt = inner % NQT_;
    int b  = inner / NQT_;
    int tid = threadIdx.x;
    int q0 = qt * 64;
    long long base = (long long)b * L_ * QKVS + h * HD_;

    int w = tid >> 6, lane = tid & 63;
    int l15 = lane & 15, lg = lane >> 4;
    int lrow = lane >> 3, lslot = lane & 7;
    int srow = lane;
    int sd0  = w << 4;

#pragma unroll
    for (int i = 0; i < 2; i++) {
        int cb = (w << 4) + (i << 3);
        int rr = cb + lrow;
        gload16(qkv + base + (long long)(q0 + rr) * QKVS + ((lslot ^ (rr & 7)) << 3),
                lQ + (cb << 6));
    }
    __syncthreads();

    int qrow = (w << 4) + l15;
    short8 qf[2];
#pragma unroll
    for (int ks = 0; ks < 2; ks++) {
        int slot = (ks << 2) + lg;
        qf[ks] = *(const short8*)(lQ + qrow * 64 + ((slot ^ (qrow & 7)) << 3));
    }
    // all of this wave's Q reads retired before crossing the first loop
    // barrier -> safe to alias lQ as the P scratch afterwards.
    asm volatile("s_waitcnt lgkmcnt(0)" ::: "memory");
    unsigned short* lPw = lQ + (w << 10);  // per-wave 16x64 P scratch (aliases Q)

    short8 ones;                           // bf16 1.0 x8 (B fragment for l-sum)
#pragma unroll
    for (int j = 0; j < 8; j++) ones[j] = (short)0x3F80;

    float m[4];
    f32x4 lacc = (f32x4)0.f;               // row-sum of bf16 P (same C layout)
    f32x4 oacc[4];
#pragma unroll
    for (int r = 0; r < 4; r++) m[r] = -1e30f;
#pragma unroll
    for (int nf = 0; nf < 4; nf++) oacc[nf] = (f32x4)0.f;

    for (int kt = 0; kt < NQT_; kt++) {
        int k0 = kt * 64;
        __syncthreads();
#pragma unroll
        for (int i = 0; i < 2; i++) {
            int cb = (w << 4) + (i << 3);
            int rr = cb + lrow;
            gload16(qkv + base + 512 + (long long)(k0 + rr) * QKVS + ((lslot ^ (rr & 7)) << 3),
                    lK + (cb << 6));
        }
        {
            int gr = k0 + srow;
            short8 v0 = (short8)0, v1 = (short8)0;
            if (gr < L_) {
                const unsigned short* pv = qkv + base + 1024 + (long long)gr * QKVS + sd0;
                v0 = *(const short8*)pv;
                v1 = *(const short8*)(pv + 8);
            }
            int ts = srow >> 3, t7 = srow & 7;
#pragma unroll
            for (int i = 0; i < 8; i++) {
                int d = sd0 + i;
                lV[d * 64 + ((ts ^ (d & 7)) << 3) + t7] = (unsigned short)v0[i];
            }
#pragma unroll
            for (int i = 0; i < 8; i++) {
                int d = sd0 + 8 + i;
                lV[d * 64 + ((ts ^ (d & 7)) << 3) + t7] = (unsigned short)v1[i];
            }
        }
        __syncthreads();

        f32x4 acc[4];
#pragma unroll
        for (int nf = 0; nf < 4; nf++) {
            acc[nf] = (f32x4)0.f;
            int tok = (nf << 4) + l15;
            int key = tok & 7;
#pragma unroll
            for (int ks = 0; ks < 2; ks++) {
                int slot = (ks << 2) + lg;
                short8 kf = *(const short8*)(lK + tok * 64 + ((slot ^ key) << 3));
                acc[nf] = __builtin_amdgcn_mfma_f32_16x16x32_bf16(qf[ks], kf, acc[nf], 0, 0, 0);
            }
        }
        // ---- mask (last kv-tile only: tokens < 768 always valid) ----
        if (kt == NQT_ - 1) {
#pragma unroll
            for (int nf = 0; nf < 4; nf++) {
                bool oob = (k0 + (nf << 4) + l15) >= L_;
#pragma unroll
                for (int r = 0; r < 4; r++)
                    if (oob) acc[nf][r] = -1e30f;
            }
        }
        // ---- row max ----
        float rm[4];
#pragma unroll
        for (int r = 0; r < 4; r++) rm[r] = -1e30f;
#pragma unroll
        for (int nf = 0; nf < 4; nf++) {
#pragma unroll
            for (int r = 0; r < 4; r++) rm[r] = fmaxf(rm[r], acc[nf][r]);
        }
#pragma unroll
        for (int off = 1; off < 16; off <<= 1) {
#pragma unroll
            for (int r = 0; r < 4; r++) rm[r] = fmaxf(rm[r], __shfl_xor(rm[r], off));
        }
        // ---- defer-max (T13): rescale only if some row grew by >8 (log2) ----
        bool need = false;
#pragma unroll
        for (int r = 0; r < 4; r++) need = need || (rm[r] > m[r] + 8.0f);
        if (__ballot(need)) {
#pragma unroll
            for (int r = 0; r < 4; r++) {
                float mn = fmaxf(m[r], rm[r]);
                float sc = ex2(m[r] - mn);
                m[r] = mn;
                lacc[r] *= sc;
#pragma unroll
                for (int nf = 0; nf < 4; nf++) oacc[nf][r] *= sc;
            }
        }
        // ---- P = exp2(S-m) -> per-wave LDS (bf16) ----
#pragma unroll
        for (int nf = 0; nf < 4; nf++) {
            int tok = (nf << 4) + l15;
            int slot = tok >> 3, t7 = tok & 7;
#pragma unroll
            for (int r = 0; r < 4; r++) {
                float p = ex2(acc[nf][r] - m[r]);
                int row = (lg << 2) + r;
                lPw[row * 64 + ((slot ^ (row & 7)) << 3) + t7] = f2bf(p);
            }
        }
        // ---- PV + l-sum (wave-private lPw: in-order DS, no barrier) ----
#pragma unroll
        for (int ks = 0; ks < 2; ks++) {
            int slot = (ks << 2) + lg;
            short8 pa = *(const short8*)(lPw + l15 * 64 + ((slot ^ (l15 & 7)) << 3));
            lacc = __builtin_amdgcn_mfma_f32_16x16x32_bf16(pa, ones, lacc, 0, 0, 0);
#pragma unroll
            for (int nf = 0; nf < 4; nf++) {
                int d = (nf << 4) + l15;
                short8 vb = *(const short8*)(lV + d * 64 + ((slot ^ (d & 7)) << 3));
                oacc[nf] = __builtin_amdgcn_mfma_f32_16x16x32_bf16(pa, vb, oacc[nf], 0, 0, 0);
            }
        }
    }
    long long obase = (long long)b * L_ * D_ + h * HD_;
#pragma unroll
    for (int r = 0; r < 4; r++) {
        int gr = q0 + (w << 4) + (lg << 2) + r;
        if (gr >= L_) continue;
        float inv = 1.f / lacc[r];
        long long ob = obase + (long long)gr * D_;
#pragma unroll
        for (int nf = 0; nf < 4; nf++)
            out[ob + (nf << 4) + l15] = f2bf(oacc[nf][r] * inv);
    }
}

// ---------------------------------------------------------------------------
// gemm launcher: 1D grid + XCD swizzle, 512 threads. mode 0 iff G>1.
// ---------------------------------------------------------------------------
static inline void gemm(hipStream_t st, const unsigned short* A, const unsigned short* WTp,
                        const float* b0, const float* b1, const float* b2,
                        const float* res, const float* xg, void* C,
                        int M, int N, int K, int ldwk, int G,
                        long long sAb, long long sWb, long long sBb,
                        long long sRb, long long sCb,
                        float alpha, float alpha1, int relu, int biasmode,
                        int resmode, int outbf16)
{
    int NX = N / 128;
    int NY = (M + 127) >> 7;
    int mode = (G > 1) ? 0 : 1;
    int NYp = mode ? ((NY + 7) & ~7) : NY;
    int nblk = mode ? (NYp * NX) : (G * NY * NX);
    k_gemm_mfma<<<nblk, 512, 0, st>>>(A, WTp, b0, b1, b2, res, xg, C,
                                      M, N, K, ldwk, NX, NY, mode,
                                      sAb, sWb, sBb, sRb, sCb,
                                      alpha, alpha1, relu, biasmode, resmode, outbf16);
}

extern "C" void kernel_launch(void* const* d_in, const int* in_sizes, int n_in,
                              void* d_out, int out_size, void* d_ws, size_t ws_size,
                              hipStream_t stream)
{
    (void)in_sizes; (void)n_in; (void)out_size; (void)ws_size;
    const float* x      = (const float*)d_in[0];
    const float* g_ln_g = (const float*)d_in[2];
    const float* g_ln_b = (const float*)d_in[3];
    const float* Wq = (const float*)d_in[4];
    const float* Wk = (const float*)d_in[5];
    const float* Wv = (const float*)d_in[6];
    const float* Wo = (const float*)d_in[7];
    const float* bq = (const float*)d_in[8];
    const float* bk = (const float*)d_in[9];
    const float* bv = (const float*)d_in[10];
    const float* bo = (const float*)d_in[11];
    const float* f_ln_g = (const float*)d_in[12];
    const float* f_ln_b = (const float*)d_in[13];
    const float* W1 = (const float*)d_in[14];
    const float* b1 = (const float*)d_in[15];
    const float* W2 = (const float*)d_in[16];
    const float* b2 = (const float*)d_in[17];
    const float* c_ln_g = (const float*)d_in[18];
    const float* c_ln_b = (const float*)d_in[19];
    const float* cWq = (const float*)d_in[20];
    const float* cWk = (const float*)d_in[21];
    const float* cWv = (const float*)d_in[22];
    const float* cWo = (const float*)d_in[23];
    const float* cbq = (const float*)d_in[24];
    const float* cbk = (const float*)d_in[25];
    const float* cbv = (const float*)d_in[26];
    const float* cbo = (const float*)d_in[27];
    const float* cf_ln_g = (const float*)d_in[28];
    const float* cf_ln_b = (const float*)d_in[29];
    const float* cW1 = (const float*)d_in[30];
    const float* cb1 = (const float*)d_in[31];
    const float* cW2 = (const float*)d_in[32];
    const float* cb2 = (const float*)d_in[33];

    // ---- workspace layout (236 MB) ----
    char* wsb = (char*)d_ws;
    float*          bA   = (float*)wsb;                              // 64MB f32: hcl -> clips_out -> h
    unsigned short* bB   = (unsigned short*)(wsb + (64ll  << 20));   // 32MB bf16 activations
    unsigned short* bQKV = (unsigned short*)(wsb + (96ll  << 20));   // 92MB: fused qkv / fmid chunks
    unsigned short* wT   = (unsigned short*)(wsb + (188ll << 20));   // 48MB: weight transposes

    const long long sA   = (long long)MC_ * D_;
    const long long sQKV = (long long)MC_ * QKVS;
    const long long sWW  = (long long)D_ * D_;
    const int MG = B_ * L_;

    // ================= clip path =================
    k_ln<<<B_ * MC_, 256, 0, stream>>>(x, bB, c_ln_g, c_ln_b, MC_, D_, 2);   // cn (fused gather)
    k_wt_stack<<<dim3(16, 16, 3 * B_), 256, 0, stream>>>(cWq, cWk, cWv, nullptr,
                                                         wT, B_, 3, sWW);
    gemm(stream, bB, wT, cbq, cbk, cbv, nullptr, nullptr, bQKV,
         MC_, QKVS, D_, D_, B_, sA, 3 * sWW, D_, 0, sQKV,
         QS, 1.0f, 0, 3, 0, 1);                                              // fused clip QKV
    k_clip_attn<<<B_ * NC_ * H_, 256, 0, stream>>>(bQKV, bB);                // ctx -> bB
    k_wt<<<dim3(16, 16, B_), 256, 0, stream>>>(cWo, wT, D_, D_, sWW, sWW);
    gemm(stream, bB, wT, cbo, nullptr, nullptr, nullptr, x, bA,
         MC_, D_, D_, D_, B_, sA, sWW, D_, 0, sA,
         1.0f, 1.0f, 0, 1, 2, 0);                                            // hcl f32 -> bA
    k_ln<<<B_ * MC_, 256, 0, stream>>>(bA, bB, cf_ln_g, cf_ln_b, MC_, D_, 0); // fn
    for (int c = 0; c < 2; c++) {   // clip FFN, 2 chunks of 1024
        k_wt<<<dim3(32, 16, B_), 256, 0, stream>>>(cW1 + c * 1024, wT, FF_, D_,
                                                   (long long)D_ * FF_, 1024ll * D_);
        gemm(stream, bB, wT, cb1 + c * 1024, nullptr, nullptr, nullptr, nullptr, bQKV,
             MC_, 1024, D_, D_, B_, sA, 1024ll * D_, FF_, 0, (long long)MC_ * 1024,
             1.0f, 1.0f, 1, 1, 0, 1);                                        // fmid chunk (relu)
        k_wt<<<dim3(16, 32, B_), 256, 0, stream>>>(cW2 + (long long)c * 1024 * D_, wT,
                                                   D_, 1024, (long long)FF_ * D_,
                                                   (long long)D_ * 1024);
        gemm(stream, bQKV, wT, cb2, nullptr, nullptr, bA, nullptr, bA,
             MC_, D_, 1024, 1024, B_, (long long)MC_ * 1024, (long long)D_ * 1024,
             D_, sA, sA, 1.0f, 1.0f, 0, (c == 0) ? 1 : 0, 1, 0);             // clips_out in-place bA
    }

    // ================= global path =================
    unsigned short* gQKVO = wT;                    // [2048][512]
    unsigned short* gW1   = wT + 4 * 262144;       // [2048][512]
    unsigned short* gW2   = wT + 8 * 262144;       // [512][2048]
    k_wt_stack<<<dim3(16, 16, 4), 256, 0, stream>>>(Wq, Wk, Wv, Wo, gQKVO, 1, 4, 0);
    k_wt<<<dim3(64, 16, 1), 256, 0, stream>>>(W1, gW1, FF_, D_, 0, 0);
    k_wt<<<dim3(16, 64, 1), 256, 0, stream>>>(W2, gW2, D_, FF_, 0, 0);

    k_ln<<<MG, 256, 0, stream>>>(bA, bB, g_ln_g, g_ln_b, L_, 0, 1);          // xn (x_rec gather)
    gemm(stream, bB, gQKVO, bq, bk, bv, nullptr, nullptr, bQKV,
         MG, QKVS, D_, D_, 1, 0, 0, 0, 0, 0,
         QS, 1.0f, 0, 3, 0, 1);                                              // fused global QKV
    k_flash_mfma<<<B_ * H_ * NQT_, 256, 0, stream>>>(bQKV, bB);              // ctx2 -> bB
    gemm(stream, bB, gQKVO + 3 * 262144, bo, nullptr, nullptr, x, nullptr, bA,
         MG, D_, D_, D_, 1, 0, 0, 0, 0, 0,
         1.0f, 1.0f, 0, 1, 1, 0);                                            // h f32 -> bA (res=x)
    k_ln<<<MG, 256, 0, stream>>>(bA, bB, f_ln_g, f_ln_b, MG, 0, 0);          // hn
    for (int c = 0; c < 2; c++) {    // global FFN, 2 chunks of 1024
        gemm(stream, bB, gW1 + (long long)c * 1024 * 512, b1 + c * 1024,
             nullptr, nullptr, nullptr, nullptr, bQKV,
             MG, 1024, D_, D_, 1, 0, 0, 0, 0, 0,
             1.0f, 1.0f, 1, 1, 0, 1);                                        // mid2 chunk (relu)
        gemm(stream, bQKV, gW2 + c * 1024, b2, nullptr, nullptr,
             (c == 0) ? bA : (float*)d_out, nullptr, d_out,
             MG, D_, 1024, FF_, 1, 0, 0, 0, 0, 0,
             1.0f, 1.0f, 0, (c == 0) ? 1 : 0, 1, 0);                         // out (in-place c=1)
    }
}

// Round 25
// 1380.792 us; speedup vs baseline: 1.0012x; 1.0012x over previous
//
#include <hip/hip_runtime.h>

#define B_   32
#define L_   796
#define D_   512
#define H_   8
#define HD_  64
#define FF_  2048
#define CS_  16
#define STR_ 13
#define NC_  61
#define NQT_ 13
#define MC_  976            // NC_*CS_ rows per batch (clip path)
#define QKVS 1536           // fused QKV row stride
#define QS   (0.125f * 1.44269504f)   // 1/sqrt(64) * log2(e)  -> exp2 softmax

typedef __attribute__((ext_vector_type(8))) short short8;
typedef __attribute__((ext_vector_type(4))) short short4v;
typedef __attribute__((ext_vector_type(4))) float f32x4;

__device__ __forceinline__ unsigned short f2bf(float x) {
    unsigned u = __float_as_uint(x);
    unsigned r = u + 0x7FFFu + ((u >> 16) & 1u);   // RNE
    return (unsigned short)(r >> 16);
}
__device__ __forceinline__ float bf2f(unsigned short h) {
    return __uint_as_float(((unsigned)h) << 16);
}
__device__ __forceinline__ float ex2(float x) {      // native v_exp_f32 (2^x)
    return __builtin_amdgcn_exp2f(x);
}
__device__ __forceinline__ void gload16(const unsigned short* g, unsigned short* l) {
    __builtin_amdgcn_global_load_lds(
        (const __attribute__((address_space(1))) void*)g,
        (__attribute__((address_space(3))) void*)l, 16, 0, 0);
}

// ---------------------------------------------------------------------------
// LayerNorm D=512, f32 in -> bf16 out.
// gather=0: direct rows; gather=1: x_rec remap; gather=2: clip build from x.
// ---------------------------------------------------------------------------
__global__ __launch_bounds__(256) void k_ln(const float* __restrict__ in,
                                            unsigned short* __restrict__ out,
                                            const float* __restrict__ gamma,
                                            const float* __restrict__ beta,
                                            int rows_per_batch, int gstride, int gather)
{
    __shared__ float red[8];
    long long row = blockIdx.x;
    int tid = threadIdx.x;
    int b;
    float v0, v1;
    if (gather == 2) {
        b = (int)(row / MC_);
        int rr = (int)(row % MC_);
        int n = rr >> 4, c = rr & 15;
        long long xb = (long long)b * L_ * D_;
        int d0 = tid, st0, sd0;
        if (d0 < 128) { st0 = n * STR_ + c; sd0 = d0; }
        else { int j = d0 - 128; st0 = n * STR_ + (j & 15); sd0 = 128 + ((j >> 4) << 4) + c; }
        v0 = in[xb + (long long)st0 * D_ + sd0];
        int j1 = tid + 128;                 // (tid+256)-128
        int st1 = n * STR_ + (j1 & 15), sd1 = 128 + ((j1 >> 4) << 4) + c;
        v1 = in[xb + (long long)st1 * D_ + sd1];
    } else {
        long long srow = row;
        if (gather == 1) {
            int p = (int)(row % L_);
            b = (int)(row / L_);
            int ci = p / STR_; if (ci > NC_ - 1) ci = NC_ - 1;
            srow = ((long long)b * NC_ + ci) * CS_ + (p - ci * STR_);
        } else {
            b = (int)(row / rows_per_batch);
        }
        const float* xr = in + srow * D_;
        v0 = xr[tid]; v1 = xr[tid + 256];
    }
    float s = v0 + v1;
#pragma unroll
    for (int off = 1; off < 64; off <<= 1) s += __shfl_xor(s, off);
    if ((tid & 63) == 0) red[tid >> 6] = s;
    __syncthreads();
    float mean = (red[0] + red[1] + red[2] + red[3]) * (1.0f / 512.0f);
    float d0 = v0 - mean, d1 = v1 - mean;
    float vv = d0 * d0 + d1 * d1;
#pragma unroll
    for (int off = 1; off < 64; off <<= 1) vv += __shfl_xor(vv, off);
    if ((tid & 63) == 0) red[4 + (tid >> 6)] = vv;
    __syncthreads();
    float var = (red[4] + red[5] + red[6] + red[7]) * (1.0f / 512.0f);
    float rstd = rsqrtf(var + 1e-6f);
    const float* g  = gamma + (long long)b * gstride;
    const float* bt = beta  + (long long)b * gstride;
    unsigned short* o = out + row * D_;
    o[tid]       = f2bf(d0 * rstd * g[tid]       + bt[tid]);
    o[tid + 256] = f2bf(d1 * rstd * g[tid + 256] + bt[tid + 256]);
}

// ---------------------------------------------------------------------------
// Weight transpose+convert: W f32 [K x N] (row stride rowStride) -> T bf16
// [N][K] (row stride tStride). grid (N/32, K/32, G).
// ---------------------------------------------------------------------------
__global__ __launch_bounds__(256) void k_wt(const float* __restrict__ W,
                                            unsigned short* __restrict__ T,
                                            int rowStride, int tStride,
                                            long long sWb, long long sTb)
{
    __shared__ float t[32][33];
    int z = blockIdx.z;
    const float* Wz = W + (long long)z * sWb;
    unsigned short* Tz = T + (long long)z * sTb;
    int n0 = blockIdx.x << 5, k0 = blockIdx.y << 5;
    int tx = threadIdx.x & 31, ty = threadIdx.x >> 5;
#pragma unroll
    for (int i = 0; i < 4; i++) {
        int k = ty + (i << 3);
        t[k][tx] = Wz[(long long)(k0 + k) * rowStride + n0 + tx];
    }
    __syncthreads();
#pragma unroll
    for (int i = 0; i < 4; i++) {
        int n = ty + (i << 3);
        Tz[(long long)(n0 + n) * tStride + k0 + tx] = f2bf(t[tx][n]);
    }
}

// Stacked transpose of up to 4 square 512x512 tensors x nb batches.
// z = tensor*nb + batch. dst: [batch][tensor*512 + n][512].
__global__ __launch_bounds__(256) void k_wt_stack(const float* __restrict__ Wa,
                                                  const float* __restrict__ Wb,
                                                  const float* __restrict__ Wc,
                                                  const float* __restrict__ Wd,
                                                  unsigned short* __restrict__ T,
                                                  int nb, int ntens, long long sWb)
{
    __shared__ float t[32][33];
    int z = blockIdx.z;
    int tt = z / nb, b = z % nb;
    const float* Wz = (tt == 0 ? Wa : tt == 1 ? Wb : tt == 2 ? Wc : Wd)
                      + (long long)b * sWb;
    unsigned short* Tz = T + ((long long)b * ntens + tt) * (512 * 512);
    int n0 = blockIdx.x << 5, k0 = blockIdx.y << 5;
    int tx = threadIdx.x & 31, ty = threadIdx.x >> 5;
#pragma unroll
    for (int i = 0; i < 4; i++) {
        int k = ty + (i << 3);
        t[k][tx] = Wz[(long long)(k0 + k) * 512 + n0 + tx];
    }
    __syncthreads();
#pragma unroll
    for (int i = 0; i < 4; i++) {
        int n = ty + (i << 3);
        Tz[(long long)(n0 + n) * 512 + k0 + tx] = f2bf(t[tx][n]);
    }
}

// ---------------------------------------------------------------------------
// bf16 MFMA GEMM — counted-vmcnt pipeline (round-12 skeleton), BK=32,
// 512 thr / 8 waves (2M x 4N, each wave 64x32 out) — round-21/23 proven best.
// NOTE: no min-waves clause (r22: forcing 8 waves/EU spilled VGPR 80->32).
// Swizzle key (r>>1)&3 (conflict-free, r20-verified: 0 conflicts).
// ---------------------------------------------------------------------------
__global__ __launch_bounds__(512) void k_gemm_mfma(
    const unsigned short* __restrict__ A, const unsigned short* __restrict__ WT,
    const float* __restrict__ b0p, const float* __restrict__ b1p,
    const float* __restrict__ b2p,
    const float* res, const float* __restrict__ xg, void* Cout,
    int M, int N, int K, int ldwk, int NX, int NYd, int mode,
    long long sAb, long long sWb, long long sBb, long long sRb, long long sCb,
    float alpha, float alpha1, int relu, int biasmode, int resmode, int outbf16)
{
    __shared__ unsigned short lds[16384];      // 32 KB: 2 x (A 8KB + W 8KB)
    int tid = threadIdx.x;

    // ---- XCD-aware decode ----
    int bid = blockIdx.x;
    int xcd = bid & 7, inner = bid >> 3;
    int x = inner % NX, t = inner / NX;
    int y, z;
    if (mode == 0) { y = t % NYd; z = (t / NYd) * 8 + xcd; }
    else           { y = t * 8 + xcd; z = 0; }
    int row0 = y << 7, col0 = x << 7;
    if (row0 >= M) return;                 // padded row-tile (mode 1)

    const unsigned short* Ab = A + z * sAb;
    const unsigned short* Wb = WT + z * sWb;

    int w = tid >> 6, lane = tid & 63;
    int wr = (w >> 2) << 6;                // 0 / 64
    int wc = (w & 3) << 5;                 // 0 / 32 / 64 / 96
    int l15 = lane & 15, lg = lane >> 4;   // lg in 0..3 = K-slot of 32
    int lrow4 = lane >> 2, lslot = lane & 3;   // staging: 16 rows x 4 slots/wave

    f32x4 acc[4][2];
#pragma unroll
    for (int i = 0; i < 4; i++)
#pragma unroll
        for (int j = 0; j < 2; j++) acc[i][j] = (f32x4)0.f;

    const int nt = K >> 5;                     // BK = 32
    int srow = (w << 4) + lrow4;               // staging row (wave w: rows w*16..+15)
    int skey = (srow >> 1) & 3;

    // ---- prologue: stage tile 0 -> buf0, tile 1 -> buf1 ----
#pragma unroll
    for (int pt = 0; pt < 2; ++pt) {
        int k0 = pt << 5;
        unsigned short* sA = lds + (pt << 13);
        unsigned short* sW = sA + 4096;
        gload16(Ab + (long long)(row0 + srow) * K + k0 + ((lslot ^ skey) << 3),
                sA + ((w << 4) << 5));
        gload16(Wb + (long long)(col0 + srow) * ldwk + k0 + ((lslot ^ skey) << 3),
                sW + ((w << 4) << 5));
    }

    for (int kt = 0; kt < nt; ++kt) {
        // (1) counted wait: tile kt's 2 loads landed; tile kt+1's stay in flight
        if (kt + 1 < nt) asm volatile("s_waitcnt vmcnt(2)" ::: "memory");
        else             asm volatile("s_waitcnt vmcnt(0)" ::: "memory");
        __builtin_amdgcn_s_barrier();      // all waves' tile-kt loads landed

        unsigned short* lA = lds + ((kt & 1) << 13);
        unsigned short* lW = lA + 4096;

        // (2) ds_read fragments of current buffer (slot = lg ^ key)
        short8 af[4], bfr[2];
#pragma unroll
        for (int mf = 0; mf < 4; mf++) {
            int r = wr + (mf << 4) + l15;
            af[mf] = *(const short8*)(lA + (r << 5) + ((lg ^ ((r >> 1) & 3)) << 3));
        }
#pragma unroll
        for (int nf = 0; nf < 2; nf++) {
            int r = wc + (nf << 4) + l15;
            bfr[nf] = *(const short8*)(lW + (r << 5) + ((lg ^ ((r >> 1) & 3)) << 3));
        }

        // (3) own reads retired -> all-waves barrier (raw: no vmcnt drain!)
        asm volatile("s_waitcnt lgkmcnt(0)" ::: "memory");
        __builtin_amdgcn_s_barrier();

        // (4) stage tile kt+2 into the buffer just consumed (now safe)
        if (kt + 2 < nt) {
            int k0 = (kt + 2) << 5;
            gload16(Ab + (long long)(row0 + srow) * K + k0 + ((lslot ^ skey) << 3),
                    lA + ((w << 4) << 5));
            gload16(Wb + (long long)(col0 + srow) * ldwk + k0 + ((lslot ^ skey) << 3),
                    lW + ((w << 4) << 5));
        }

        // (5) register-only MFMA cluster
        __builtin_amdgcn_s_setprio(1);
#pragma unroll
        for (int mf = 0; mf < 4; mf++)
#pragma unroll
            for (int nf = 0; nf < 2; nf++)
                acc[mf][nf] = __builtin_amdgcn_mfma_f32_16x16x32_bf16(
                    af[mf], bfr[nf], acc[mf][nf], 0, 0, 0);
        __builtin_amdgcn_s_setprio(0);
    }

#pragma unroll
    for (int mf = 0; mf < 4; mf++) {
#pragma unroll
        for (int reg = 0; reg < 4; reg++) {
            int gr = row0 + wr + (mf << 4) + (lg << 2) + reg;
            if (gr >= M) continue;
#pragma unroll
            for (int nf = 0; nf < 2; nf++) {
                int gc = col0 + wc + (nf << 4) + l15;
                float v = acc[mf][nf][reg];
                if (biasmode == 1) v += b0p[z * sBb + gc];
                else if (biasmode == 3) {
                    const float* bp = gc < 512 ? b0p : (gc < 1024 ? b1p : b2p);
                    v += bp[z * sBb + (gc & 511)];
                }
                v *= (gc < 512) ? alpha : alpha1;
                if (relu) v = fmaxf(v, 0.f);
                if (resmode == 1) {
                    v += res[z * sRb + (long long)gr * N + gc];
                } else if (resmode == 2) {
                    int n = gr >> 4, c = gr & 15;
                    int st, sd;
                    if (gc < 128) { st = n * STR_ + c; sd = gc; }
                    else {
                        int jj = gc - 128;
                        st = n * STR_ + (jj & 15);
                        sd = 128 + ((jj >> 4) << 4) + c;
                    }
                    v += xg[((long long)z * L_ + st) * D_ + sd];
                }
                long long co = z * sCb + (long long)gr * N + gc;
                if (outbf16) ((unsigned short*)Cout)[co] = f2bf(v);
                else         ((float*)Cout)[co] = v;
            }
        }
    }
}

// ---------------------------------------------------------------------------
// Clip attention on fused QKV (stride QKVS, offsets 0/512/1024), exp2 softmax.
// Vectorized: one short4 load per tensor per thread; packed ushort4 ctx store.
// ---------------------------------------------------------------------------
__global__ __launch_bounds__(256) void k_clip_attn(const unsigned short* __restrict__ qkv,
                                                   unsigned short* __restrict__ ctx)
{
    __shared__ float qs[CS_][65], ks[CS_][65], vs[CS_][65], ps[CS_][17];
    int id = blockIdx.x;
    int h = id & (H_ - 1);
    int n = (id / H_) % NC_;
    int b = id / (H_ * NC_);
    long long base = (((long long)b * NC_ + n) * CS_) * QKVS + h * HD_;
    int tid = threadIdx.x;
    {
        int e = tid << 2;                  // 4 contiguous elems (same row)
        int r = e >> 6, c = e & 63;
        long long ro = base + (long long)r * QKVS + c;
        short4v qv = *(const short4v*)(qkv + ro);
        short4v kv = *(const short4v*)(qkv + ro + 512);
        short4v vv = *(const short4v*)(qkv + ro + 1024);
#pragma unroll
        for (int j = 0; j < 4; j++) {
            qs[r][c + j] = bf2f((unsigned short)qv[j]);
            ks[r][c + j] = bf2f((unsigned short)kv[j]);
            vs[r][c + j] = bf2f((unsigned short)vv[j]);
        }
    }
    __syncthreads();
    int qr = tid >> 4, kc = tid & 15;
    float s = 0.f;
#pragma unroll
    for (int d = 0; d < HD_; d++) s += qs[qr][d] * ks[kc][d];
    float m = s;
#pragma unroll
    for (int off = 1; off < 16; off <<= 1) m = fmaxf(m, __shfl_xor(m, off));
    float e = ex2(s - m);
    float sum = e;
#pragma unroll
    for (int off = 1; off < 16; off <<= 1) sum += __shfl_xor(sum, off);
    ps[qr][kc] = e / sum;
    __syncthreads();
    int dg = (tid & 15) * 4;
    float o0 = 0, o1 = 0, o2 = 0, o3 = 0;
#pragma unroll
    for (int kk = 0; kk < CS_; kk++) {
        float pp = ps[qr][kk];
        o0 += pp * vs[kk][dg + 0];
        o1 += pp * vs[kk][dg + 1];
        o2 += pp * vs[kk][dg + 2];
        o3 += pp * vs[kk][dg + 3];
    }
    long long ob = ((((long long)b * NC_ + n) * CS_) + qr) * D_ + h * HD_ + dg;
    short4v ov;
    ov[0] = (short)f2bf(o0); ov[1] = (short)f2bf(o1);
    ov[2] = (short)f2bf(o2); ov[3] = (short)f2bf(o3);
    *(short4v*)(ctx + ob) = ov;
}

// ---------------------------------------------------------------------------
// Global flash attention (MFMA, exp2 softmax) on fused QKV buffer.
// Round-23 proven best flash (60 VGPR, 41% occ): shuffle-based l.
// Block = (b, h, 64-row q-tile), 4 waves x 16 q-rows. LDS 24KB (Q aliased as
// P scratch after qf load + lgkmcnt(0)). Mask only last kv-tile. Defer-max
// (T13, THR=8 log2). XCD swizzle: h = bid&7.
// NOTE r24: MFMA l-sum cut VALUBusy 46->40% but VGPR 60->72 dropped
// occupancy 41->30% -> net null; reverted (latency-bound: registers win).
// ---------------------------------------------------------------------------
__global__ __launch_bounds__(256) void k_flash_mfma(
    const unsigned short* __restrict__ qkv,
    unsigned short* __restrict__ out)
{
    __shared__ unsigned short sh[12288];   // 24KB: [0,8K)=Q then P; K; V
    unsigned short* lQ = sh;               // 64x64 Q tile (dead after qf load)
    unsigned short* lK = sh + 4096;
    unsigned short* lV = sh + 8192;
    int bid = blockIdx.x;
    int h  = bid & 7;
    int inner = bid >> 3;
    int qt = inner % NQT_;
    int b  = inner / NQT_;
    int tid = threadIdx.x;
    int q0 = qt * 64;
    long long base = (long long)b * L_ * QKVS + h * HD_;

    int w = tid >> 6, lane = tid & 63;
    int l15 = lane & 15, lg = lane >> 4;
    int lrow = lane >> 3, lslot = lane & 7;
    int srow = lane;
    int sd0  = w << 4;

#pragma unroll
    for (int i = 0; i < 2; i++) {
        int cb = (w << 4) + (i << 3);
        int rr = cb + lrow;
        gload16(qkv + base + (long long)(q0 + rr) * QKVS + ((lslot ^ (rr & 7)) << 3),
                lQ + (cb << 6));
    }
    __syncthreads();

    int qrow = (w << 4) + l15;
    short8 qf[2];
#pragma unroll
    for (int ks = 0; ks < 2; ks++) {
        int slot = (ks << 2) + lg;
        qf[ks] = *(const short8*)(lQ + qrow * 64 + ((slot ^ (qrow & 7)) << 3));
    }
    // all of this wave's Q reads retired before crossing the first loop
    // barrier -> safe to alias lQ as the P scratch afterwards.
    asm volatile("s_waitcnt lgkmcnt(0)" ::: "memory");
    unsigned short* lPw = lQ + (w << 10);  // per-wave 16x64 P scratch (aliases Q)

    float m[4], l[4];
    f32x4 oacc[4];
#pragma unroll
    for (int r = 0; r < 4; r++) { m[r] = -1e30f; l[r] = 0.f; }
#pragma unroll
    for (int nf = 0; nf < 4; nf++) oacc[nf] = (f32x4)0.f;

    for (int kt = 0; kt < NQT_; kt++) {
        int k0 = kt * 64;
        __syncthreads();
#pragma unroll
        for (int i = 0; i < 2; i++) {
            int cb = (w << 4) + (i << 3);
            int rr = cb + lrow;
            gload16(qkv + base + 512 + (long long)(k0 + rr) * QKVS + ((lslot ^ (rr & 7)) << 3),
                    lK + (cb << 6));
        }
        {
            int gr = k0 + srow;
            short8 v0 = (short8)0, v1 = (short8)0;
            if (gr < L_) {
                const unsigned short* pv = qkv + base + 1024 + (long long)gr * QKVS + sd0;
                v0 = *(const short8*)pv;
                v1 = *(const short8*)(pv + 8);
            }
            int ts = srow >> 3, t7 = srow & 7;
#pragma unroll
            for (int i = 0; i < 8; i++) {
                int d = sd0 + i;
                lV[d * 64 + ((ts ^ (d & 7)) << 3) + t7] = (unsigned short)v0[i];
            }
#pragma unroll
            for (int i = 0; i < 8; i++) {
                int d = sd0 + 8 + i;
                lV[d * 64 + ((ts ^ (d & 7)) << 3) + t7] = (unsigned short)v1[i];
            }
        }
        __syncthreads();

        f32x4 acc[4];
#pragma unroll
        for (int nf = 0; nf < 4; nf++) {
            acc[nf] = (f32x4)0.f;
            int tok = (nf << 4) + l15;
            int key = tok & 7;
#pragma unroll
            for (int ks = 0; ks < 2; ks++) {
                int slot = (ks << 2) + lg;
                short8 kf = *(const short8*)(lK + tok * 64 + ((slot ^ key) << 3));
                acc[nf] = __builtin_amdgcn_mfma_f32_16x16x32_bf16(qf[ks], kf, acc[nf], 0, 0, 0);
            }
        }
        // ---- mask (last kv-tile only: tokens < 768 always valid) ----
        if (kt == NQT_ - 1) {
#pragma unroll
            for (int nf = 0; nf < 4; nf++) {
                bool oob = (k0 + (nf << 4) + l15) >= L_;
#pragma unroll
                for (int r = 0; r < 4; r++)
                    if (oob) acc[nf][r] = -1e30f;
            }
        }
        // ---- row max ----
        float rm[4];
#pragma unroll
        for (int r = 0; r < 4; r++) rm[r] = -1e30f;
#pragma unroll
        for (int nf = 0; nf < 4; nf++) {
#pragma unroll
            for (int r = 0; r < 4; r++) rm[r] = fmaxf(rm[r], acc[nf][r]);
        }
#pragma unroll
        for (int off = 1; off < 16; off <<= 1) {
#pragma unroll
            for (int r = 0; r < 4; r++) rm[r] = fmaxf(rm[r], __shfl_xor(rm[r], off));
        }
        // ---- defer-max (T13): rescale only if some row grew by >8 (log2) ----
        bool need = false;
#pragma unroll
        for (int r = 0; r < 4; r++) need = need || (rm[r] > m[r] + 8.0f);
        if (__ballot(need)) {
#pragma unroll
            for (int r = 0; r < 4; r++) {
                float mn = fmaxf(m[r], rm[r]);
                float sc = ex2(m[r] - mn);
                m[r] = mn;
                l[r] *= sc;
#pragma unroll
                for (int nf = 0; nf < 4; nf++) oacc[nf][r] *= sc;
            }
        }
        // ---- P = exp2(S-m) -> per-wave LDS (bf16) ----
        float ls[4];
#pragma unroll
        for (int r = 0; r < 4; r++) ls[r] = 0.f;
#pragma unroll
        for (int nf = 0; nf < 4; nf++) {
            int tok = (nf << 4) + l15;
            int slot = tok >> 3, t7 = tok & 7;
#pragma unroll
            for (int r = 0; r < 4; r++) {
                float p = ex2(acc[nf][r] - m[r]);
                ls[r] += p;
                int row = (lg << 2) + r;
                lPw[row * 64 + ((slot ^ (row & 7)) << 3) + t7] = f2bf(p);
            }
        }
#pragma unroll
        for (int off = 1; off < 16; off <<= 1) {
#pragma unroll
            for (int r = 0; r < 4; r++) ls[r] += __shfl_xor(ls[r], off);
        }
#pragma unroll
        for (int r = 0; r < 4; r++) l[r] += ls[r];
        // ---- PV (wave-private lPw: in-order DS, no barrier needed) ----
#pragma unroll
        for (int ks = 0; ks < 2; ks++) {
            int slot = (ks << 2) + lg;
            short8 pa = *(const short8*)(lPw + l15 * 64 + ((slot ^ (l15 & 7)) << 3));
#pragma unroll
            for (int nf = 0; nf < 4; nf++) {
                int d = (nf << 4) + l15;
                short8 vb = *(const short8*)(lV + d * 64 + ((slot ^ (d & 7)) << 3));
                oacc[nf] = __builtin_amdgcn_mfma_f32_16x16x32_bf16(pa, vb, oacc[nf], 0, 0, 0);
            }
        }
    }
    long long obase = (long long)b * L_ * D_ + h * HD_;
#pragma unroll
    for (int r = 0; r < 4; r++) {
        int gr = q0 + (w << 4) + (lg << 2) + r;
        if (gr >= L_) continue;
        float inv = 1.f / l[r];
        long long ob = obase + (long long)gr * D_;
#pragma unroll
        for (int nf = 0; nf < 4; nf++)
            out[ob + (nf << 4) + l15] = f2bf(oacc[nf][r] * inv);
    }
}

// ---------------------------------------------------------------------------
// gemm launcher: 1D grid + XCD swizzle, 512 threads. mode 0 iff G>1.
// ---------------------------------------------------------------------------
static inline void gemm(hipStream_t st, const unsigned short* A, const unsigned short* WTp,
                        const float* b0, const float* b1, const float* b2,
                        const float* res, const float* xg, void* C,
                        int M, int N, int K, int ldwk, int G,
                        long long sAb, long long sWb, long long sBb,
                        long long sRb, long long sCb,
                        float alpha, float alpha1, int relu, int biasmode,
                        int resmode, int outbf16)
{
    int NX = N / 128;
    int NY = (M + 127) >> 7;
    int mode = (G > 1) ? 0 : 1;
    int NYp = mode ? ((NY + 7) & ~7) : NY;
    int nblk = mode ? (NYp * NX) : (G * NY * NX);
    k_gemm_mfma<<<nblk, 512, 0, st>>>(A, WTp, b0, b1, b2, res, xg, C,
                                      M, N, K, ldwk, NX, NY, mode,
                                      sAb, sWb, sBb, sRb, sCb,
                                      alpha, alpha1, relu, biasmode, resmode, outbf16);
}

extern "C" void kernel_launch(void* const* d_in, const int* in_sizes, int n_in,
                              void* d_out, int out_size, void* d_ws, size_t ws_size,
                              hipStream_t stream)
{
    (void)in_sizes; (void)n_in; (void)out_size; (void)ws_size;
    const float* x      = (const float*)d_in[0];
    const float* g_ln_g = (const float*)d_in[2];
    const float* g_ln_b = (const float*)d_in[3];
    const float* Wq = (const float*)d_in[4];
    const float* Wk = (const float*)d_in[5];
    const float* Wv = (const float*)d_in[6];
    const float* Wo = (const float*)d_in[7];
    const float* bq = (const float*)d_in[8];
    const float* bk = (const float*)d_in[9];
    const float* bv = (const float*)d_in[10];
    const float* bo = (const float*)d_in[11];
    const float* f_ln_g = (const float*)d_in[12];
    const float* f_ln_b = (const float*)d_in[13];
    const float* W1 = (const float*)d_in[14];
    const float* b1 = (const float*)d_in[15];
    const float* W2 = (const float*)d_in[16];
    const float* b2 = (const float*)d_in[17];
    const float* c_ln_g = (const float*)d_in[18];
    const float* c_ln_b = (const float*)d_in[19];
    const float* cWq = (const float*)d_in[20];
    const float* cWk = (const float*)d_in[21];
    const float* cWv = (const float*)d_in[22];
    const float* cWo = (const float*)d_in[23];
    const float* cbq = (const float*)d_in[24];
    const float* cbk = (const float*)d_in[25];
    const float* cbv = (const float*)d_in[26];
    const float* cbo = (const float*)d_in[27];
    const float* cf_ln_g = (const float*)d_in[28];
    const float* cf_ln_b = (const float*)d_in[29];
    const float* cW1 = (const float*)d_in[30];
    const float* cb1 = (const float*)d_in[31];
    const float* cW2 = (const float*)d_in[32];
    const float* cb2 = (const float*)d_in[33];

    // ---- workspace layout (236 MB) ----
    char* wsb = (char*)d_ws;
    float*          bA   = (float*)wsb;                              // 64MB f32: hcl -> clips_out -> h
    unsigned short* bB   = (unsigned short*)(wsb + (64ll  << 20));   // 32MB bf16 activations
    unsigned short* bQKV = (unsigned short*)(wsb + (96ll  << 20));   // 92MB: fused qkv / fmid chunks
    unsigned short* wT   = (unsigned short*)(wsb + (188ll << 20));   // 48MB: weight transposes

    const long long sA   = (long long)MC_ * D_;
    const long long sQKV = (long long)MC_ * QKVS;
    const long long sWW  = (long long)D_ * D_;
    const int MG = B_ * L_;

    // ================= clip path =================
    k_ln<<<B_ * MC_, 256, 0, stream>>>(x, bB, c_ln_g, c_ln_b, MC_, D_, 2);   // cn (fused gather)
    k_wt_stack<<<dim3(16, 16, 3 * B_), 256, 0, stream>>>(cWq, cWk, cWv, nullptr,
                                                         wT, B_, 3, sWW);
    gemm(stream, bB, wT, cbq, cbk, cbv, nullptr, nullptr, bQKV,
         MC_, QKVS, D_, D_, B_, sA, 3 * sWW, D_, 0, sQKV,
         QS, 1.0f, 0, 3, 0, 1);                                              // fused clip QKV
    k_clip_attn<<<B_ * NC_ * H_, 256, 0, stream>>>(bQKV, bB);                // ctx -> bB
    k_wt<<<dim3(16, 16, B_), 256, 0, stream>>>(cWo, wT, D_, D_, sWW, sWW);
    gemm(stream, bB, wT, cbo, nullptr, nullptr, nullptr, x, bA,
         MC_, D_, D_, D_, B_, sA, sWW, D_, 0, sA,
         1.0f, 1.0f, 0, 1, 2, 0);                                            // hcl f32 -> bA
    k_ln<<<B_ * MC_, 256, 0, stream>>>(bA, bB, cf_ln_g, cf_ln_b, MC_, D_, 0); // fn
    for (int c = 0; c < 2; c++) {   // clip FFN, 2 chunks of 1024
        k_wt<<<dim3(32, 16, B_), 256, 0, stream>>>(cW1 + c * 1024, wT, FF_, D_,
                                                   (long long)D_ * FF_, 1024ll * D_);
        gemm(stream, bB, wT, cb1 + c * 1024, nullptr, nullptr, nullptr, nullptr, bQKV,
             MC_, 1024, D_, D_, B_, sA, 1024ll * D_, FF_, 0, (long long)MC_ * 1024,
             1.0f, 1.0f, 1, 1, 0, 1);                                        // fmid chunk (relu)
        k_wt<<<dim3(16, 32, B_), 256, 0, stream>>>(cW2 + (long long)c * 1024 * D_, wT,
                                                   D_, 1024, (long long)FF_ * D_,
                                                   (long long)D_ * 1024);
        gemm(stream, bQKV, wT, cb2, nullptr, nullptr, bA, nullptr, bA,
             MC_, D_, 1024, 1024, B_, (long long)MC_ * 1024, (long long)D_ * 1024,
             D_, sA, sA, 1.0f, 1.0f, 0, (c == 0) ? 1 : 0, 1, 0);             // clips_out in-place bA
    }

    // ================= global path =================
    unsigned short* gQKVO = wT;                    // [2048][512]
    unsigned short* gW1   = wT + 4 * 262144;       // [2048][512]
    unsigned short* gW2   = wT + 8 * 262144;       // [512][2048]
    k_wt_stack<<<dim3(16, 16, 4), 256, 0, stream>>>(Wq, Wk, Wv, Wo, gQKVO, 1, 4, 0);
    k_wt<<<dim3(64, 16, 1), 256, 0, stream>>>(W1, gW1, FF_, D_, 0, 0);
    k_wt<<<dim3(16, 64, 1), 256, 0, stream>>>(W2, gW2, D_, FF_, 0, 0);

    k_ln<<<MG, 256, 0, stream>>>(bA, bB, g_ln_g, g_ln_b, L_, 0, 1);          // xn (x_rec gather)
    gemm(stream, bB, gQKVO, bq, bk, bv, nullptr, nullptr, bQKV,
         MG, QKVS, D_, D_, 1, 0, 0, 0, 0, 0,
         QS, 1.0f, 0, 3, 0, 1);                                              // fused global QKV
    k_flash_mfma<<<B_ * H_ * NQT_, 256, 0, stream>>>(bQKV, bB);              // ctx2 -> bB
    gemm(stream, bB, gQKVO + 3 * 262144, bo, nullptr, nullptr, x, nullptr, bA,
         MG, D_, D_, D_, 1, 0, 0, 0, 0, 0,
         1.0f, 1.0f, 0, 1, 1, 0);                                            // h f32 -> bA (res=x)
    k_ln<<<MG, 256, 0, stream>>>(bA, bB, f_ln_g, f_ln_b, MG, 0, 0);          // hn
    for (int c = 0; c < 2; c++) {    // global FFN, 2 chunks of 1024
        gemm(stream, bB, gW1 + (long long)c * 1024 * 512, b1 + c * 1024,
             nullptr, nullptr, nullptr, nullptr, bQKV,
             MG, 1024, D_, D_, 1, 0, 0, 0, 0, 0,
             1.0f, 1.0f, 1, 1, 0, 1);                                        // mid2 chunk (relu)
        gemm(stream, bQKV, gW2 + c * 1024, b2, nullptr, nullptr,
             (c == 0) ? bA : (float*)d_out, nullptr, d_out,
             MG, D_, 1024, FF_, 1, 0, 0, 0, 0, 0,
             1.0f, 1.0f, 0, (c == 0) ? 1 : 0, 1, 0);                         // out (in-place c=1)
    }
}

// Round 26
// 1380.478 us; speedup vs baseline: 1.0014x; 1.0002x over previous
//
#include <hip/hip_runtime.h>

#define B_   32
#define L_   796
#define D_   512
#define H_   8
#define HD_  64
#define FF_  2048
#define CS_  16
#define STR_ 13
#define NC_  61
#define NQT_ 13             // kv-tiles of 64
#define NQT2_ 7             // q-tiles of 128 rows (ceil(796/128))
#define MC_  976            // NC_*CS_ rows per batch (clip path)
#define QKVS 1536           // fused QKV row stride
#define QS   (0.125f * 1.44269504f)   // 1/sqrt(64) * log2(e)  -> exp2 softmax

typedef __attribute__((ext_vector_type(8))) short short8;
typedef __attribute__((ext_vector_type(4))) short short4v;
typedef __attribute__((ext_vector_type(4))) float f32x4;

__device__ __forceinline__ unsigned short f2bf(float x) {
    unsigned u = __float_as_uint(x);
    unsigned r = u + 0x7FFFu + ((u >> 16) & 1u);   // RNE
    return (unsigned short)(r >> 16);
}
__device__ __forceinline__ float bf2f(unsigned short h) {
    return __uint_as_float(((unsigned)h) << 16);
}
__device__ __forceinline__ float ex2(float x) {      // native v_exp_f32 (2^x)
    return __builtin_amdgcn_exp2f(x);
}
__device__ __forceinline__ void gload16(const unsigned short* g, unsigned short* l) {
    __builtin_amdgcn_global_load_lds(
        (const __attribute__((address_space(1))) void*)g,
        (__attribute__((address_space(3))) void*)l, 16, 0, 0);
}

// ---------------------------------------------------------------------------
// LayerNorm D=512, f32 in -> bf16 out.
// gather=0: direct rows; gather=1: x_rec remap; gather=2: clip build from x.
// ---------------------------------------------------------------------------
__global__ __launch_bounds__(256) void k_ln(const float* __restrict__ in,
                                            unsigned short* __restrict__ out,
                                            const float* __restrict__ gamma,
                                            const float* __restrict__ beta,
                                            int rows_per_batch, int gstride, int gather)
{
    __shared__ float red[8];
    long long row = blockIdx.x;
    int tid = threadIdx.x;
    int b;
    float v0, v1;
    if (gather == 2) {
        b = (int)(row / MC_);
        int rr = (int)(row % MC_);
        int n = rr >> 4, c = rr & 15;
        long long xb = (long long)b * L_ * D_;
        int d0 = tid, st0, sd0;
        if (d0 < 128) { st0 = n * STR_ + c; sd0 = d0; }
        else { int j = d0 - 128; st0 = n * STR_ + (j & 15); sd0 = 128 + ((j >> 4) << 4) + c; }
        v0 = in[xb + (long long)st0 * D_ + sd0];
        int j1 = tid + 128;                 // (tid+256)-128
        int st1 = n * STR_ + (j1 & 15), sd1 = 128 + ((j1 >> 4) << 4) + c;
        v1 = in[xb + (long long)st1 * D_ + sd1];
    } else {
        long long srow = row;
        if (gather == 1) {
            int p = (int)(row % L_);
            b = (int)(row / L_);
            int ci = p / STR_; if (ci > NC_ - 1) ci = NC_ - 1;
            srow = ((long long)b * NC_ + ci) * CS_ + (p - ci * STR_);
        } else {
            b = (int)(row / rows_per_batch);
        }
        const float* xr = in + srow * D_;
        v0 = xr[tid]; v1 = xr[tid + 256];
    }
    float s = v0 + v1;
#pragma unroll
    for (int off = 1; off < 64; off <<= 1) s += __shfl_xor(s, off);
    if ((tid & 63) == 0) red[tid >> 6] = s;
    __syncthreads();
    float mean = (red[0] + red[1] + red[2] + red[3]) * (1.0f / 512.0f);
    float d0 = v0 - mean, d1 = v1 - mean;
    float vv = d0 * d0 + d1 * d1;
#pragma unroll
    for (int off = 1; off < 64; off <<= 1) vv += __shfl_xor(vv, off);
    if ((tid & 63) == 0) red[4 + (tid >> 6)] = vv;
    __syncthreads();
    float var = (red[4] + red[5] + red[6] + red[7]) * (1.0f / 512.0f);
    float rstd = rsqrtf(var + 1e-6f);
    const float* g  = gamma + (long long)b * gstride;
    const float* bt = beta  + (long long)b * gstride;
    unsigned short* o = out + row * D_;
    o[tid]       = f2bf(d0 * rstd * g[tid]       + bt[tid]);
    o[tid + 256] = f2bf(d1 * rstd * g[tid + 256] + bt[tid + 256]);
}

// ---------------------------------------------------------------------------
// Weight transpose+convert: W f32 [K x N] (row stride rowStride) -> T bf16
// [N][K] (row stride tStride). grid (N/32, K/32, G).
// ---------------------------------------------------------------------------
__global__ __launch_bounds__(256) void k_wt(const float* __restrict__ W,
                                            unsigned short* __restrict__ T,
                                            int rowStride, int tStride,
                                            long long sWb, long long sTb)
{
    __shared__ float t[32][33];
    int z = blockIdx.z;
    const float* Wz = W + (long long)z * sWb;
    unsigned short* Tz = T + (long long)z * sTb;
    int n0 = blockIdx.x << 5, k0 = blockIdx.y << 5;
    int tx = threadIdx.x & 31, ty = threadIdx.x >> 5;
#pragma unroll
    for (int i = 0; i < 4; i++) {
        int k = ty + (i << 3);
        t[k][tx] = Wz[(long long)(k0 + k) * rowStride + n0 + tx];
    }
    __syncthreads();
#pragma unroll
    for (int i = 0; i < 4; i++) {
        int n = ty + (i << 3);
        Tz[(long long)(n0 + n) * tStride + k0 + tx] = f2bf(t[tx][n]);
    }
}

// Stacked transpose of up to 4 square 512x512 tensors x nb batches.
// z = tensor*nb + batch. dst: [batch][tensor*512 + n][512].
__global__ __launch_bounds__(256) void k_wt_stack(const float* __restrict__ Wa,
                                                  const float* __restrict__ Wb,
                                                  const float* __restrict__ Wc,
                                                  const float* __restrict__ Wd,
                                                  unsigned short* __restrict__ T,
                                                  int nb, int ntens, long long sWb)
{
    __shared__ float t[32][33];
    int z = blockIdx.z;
    int tt = z / nb, b = z % nb;
    const float* Wz = (tt == 0 ? Wa : tt == 1 ? Wb : tt == 2 ? Wc : Wd)
                      + (long long)b * sWb;
    unsigned short* Tz = T + ((long long)b * ntens + tt) * (512 * 512);
    int n0 = blockIdx.x << 5, k0 = blockIdx.y << 5;
    int tx = threadIdx.x & 31, ty = threadIdx.x >> 5;
#pragma unroll
    for (int i = 0; i < 4; i++) {
        int k = ty + (i << 3);
        t[k][tx] = Wz[(long long)(k0 + k) * 512 + n0 + tx];
    }
    __syncthreads();
#pragma unroll
    for (int i = 0; i < 4; i++) {
        int n = ty + (i << 3);
        Tz[(long long)(n0 + n) * 512 + k0 + tx] = f2bf(t[tx][n]);
    }
}

// ---------------------------------------------------------------------------
// bf16 MFMA GEMM — counted-vmcnt pipeline (round-12 skeleton), BK=32,
// 512 thr / 8 waves (2M x 4N, each wave 64x32 out) — round-21/23/25 proven.
// NOTE: no min-waves clause (r22: forcing 8 waves/EU spilled VGPR 80->32).
// Swizzle key (r>>1)&3 (conflict-free, r20-verified: 0 conflicts).
// ---------------------------------------------------------------------------
__global__ __launch_bounds__(512) void k_gemm_mfma(
    const unsigned short* __restrict__ A, const unsigned short* __restrict__ WT,
    const float* __restrict__ b0p, const float* __restrict__ b1p,
    const float* __restrict__ b2p,
    const float* res, const float* __restrict__ xg, void* Cout,
    int M, int N, int K, int ldwk, int NX, int NYd, int mode,
    long long sAb, long long sWb, long long sBb, long long sRb, long long sCb,
    float alpha, float alpha1, int relu, int biasmode, int resmode, int outbf16)
{
    __shared__ unsigned short lds[16384];      // 32 KB: 2 x (A 8KB + W 8KB)
    int tid = threadIdx.x;

    // ---- XCD-aware decode ----
    int bid = blockIdx.x;
    int xcd = bid & 7, inner = bid >> 3;
    int x = inner % NX, t = inner / NX;
    int y, z;
    if (mode == 0) { y = t % NYd; z = (t / NYd) * 8 + xcd; }
    else           { y = t * 8 + xcd; z = 0; }
    int row0 = y << 7, col0 = x << 7;
    if (row0 >= M) return;                 // padded row-tile (mode 1)

    const unsigned short* Ab = A + z * sAb;
    const unsigned short* Wb = WT + z * sWb;

    int w = tid >> 6, lane = tid & 63;
    int wr = (w >> 2) << 6;                // 0 / 64
    int wc = (w & 3) << 5;                 // 0 / 32 / 64 / 96
    int l15 = lane & 15, lg = lane >> 4;   // lg in 0..3 = K-slot of 32
    int lrow4 = lane >> 2, lslot = lane & 3;   // staging: 16 rows x 4 slots/wave

    f32x4 acc[4][2];
#pragma unroll
    for (int i = 0; i < 4; i++)
#pragma unroll
        for (int j = 0; j < 2; j++) acc[i][j] = (f32x4)0.f;

    const int nt = K >> 5;                     // BK = 32
    int srow = (w << 4) + lrow4;               // staging row (wave w: rows w*16..+15)
    int skey = (srow >> 1) & 3;

    // ---- prologue: stage tile 0 -> buf0, tile 1 -> buf1 ----
#pragma unroll
    for (int pt = 0; pt < 2; ++pt) {
        int k0 = pt << 5;
        unsigned short* sA = lds + (pt << 13);
        unsigned short* sW = sA + 4096;
        gload16(Ab + (long long)(row0 + srow) * K + k0 + ((lslot ^ skey) << 3),
                sA + ((w << 4) << 5));
        gload16(Wb + (long long)(col0 + srow) * ldwk + k0 + ((lslot ^ skey) << 3),
                sW + ((w << 4) << 5));
    }

    for (int kt = 0; kt < nt; ++kt) {
        // (1) counted wait: tile kt's 2 loads landed; tile kt+1's stay in flight
        if (kt + 1 < nt) asm volatile("s_waitcnt vmcnt(2)" ::: "memory");
        else             asm volatile("s_waitcnt vmcnt(0)" ::: "memory");
        __builtin_amdgcn_s_barrier();      // all waves' tile-kt loads landed

        unsigned short* lA = lds + ((kt & 1) << 13);
        unsigned short* lW = lA + 4096;

        // (2) ds_read fragments of current buffer (slot = lg ^ key)
        short8 af[4], bfr[2];
#pragma unroll
        for (int mf = 0; mf < 4; mf++) {
            int r = wr + (mf << 4) + l15;
            af[mf] = *(const short8*)(lA + (r << 5) + ((lg ^ ((r >> 1) & 3)) << 3));
        }
#pragma unroll
        for (int nf = 0; nf < 2; nf++) {
            int r = wc + (nf << 4) + l15;
            bfr[nf] = *(const short8*)(lW + (r << 5) + ((lg ^ ((r >> 1) & 3)) << 3));
        }

        // (3) own reads retired -> all-waves barrier (raw: no vmcnt drain!)
        asm volatile("s_waitcnt lgkmcnt(0)" ::: "memory");
        __builtin_amdgcn_s_barrier();

        // (4) stage tile kt+2 into the buffer just consumed (now safe)
        if (kt + 2 < nt) {
            int k0 = (kt + 2) << 5;
            gload16(Ab + (long long)(row0 + srow) * K + k0 + ((lslot ^ skey) << 3),
                    lA + ((w << 4) << 5));
            gload16(Wb + (long long)(col0 + srow) * ldwk + k0 + ((lslot ^ skey) << 3),
                    lW + ((w << 4) << 5));
        }

        // (5) register-only MFMA cluster
        __builtin_amdgcn_s_setprio(1);
#pragma unroll
        for (int mf = 0; mf < 4; mf++)
#pragma unroll
            for (int nf = 0; nf < 2; nf++)
                acc[mf][nf] = __builtin_amdgcn_mfma_f32_16x16x32_bf16(
                    af[mf], bfr[nf], acc[mf][nf], 0, 0, 0);
        __builtin_amdgcn_s_setprio(0);
    }

#pragma unroll
    for (int mf = 0; mf < 4; mf++) {
#pragma unroll
        for (int reg = 0; reg < 4; reg++) {
            int gr = row0 + wr + (mf << 4) + (lg << 2) + reg;
            if (gr >= M) continue;
#pragma unroll
            for (int nf = 0; nf < 2; nf++) {
                int gc = col0 + wc + (nf << 4) + l15;
                float v = acc[mf][nf][reg];
                if (biasmode == 1) v += b0p[z * sBb + gc];
                else if (biasmode == 3) {
                    const float* bp = gc < 512 ? b0p : (gc < 1024 ? b1p : b2p);
                    v += bp[z * sBb + (gc & 511)];
                }
                v *= (gc < 512) ? alpha : alpha1;
                if (relu) v = fmaxf(v, 0.f);
                if (resmode == 1) {
                    v += res[z * sRb + (long long)gr * N + gc];
                } else if (resmode == 2) {
                    int n = gr >> 4, c = gr & 15;
                    int st, sd;
                    if (gc < 128) { st = n * STR_ + c; sd = gc; }
                    else {
                        int jj = gc - 128;
                        st = n * STR_ + (jj & 15);
                        sd = 128 + ((jj >> 4) << 4) + c;
                    }
                    v += xg[((long long)z * L_ + st) * D_ + sd];
                }
                long long co = z * sCb + (long long)gr * N + gc;
                if (outbf16) ((unsigned short*)Cout)[co] = f2bf(v);
                else         ((float*)Cout)[co] = v;
            }
        }
    }
}

// ---------------------------------------------------------------------------
// Clip attention on fused QKV (stride QKVS, offsets 0/512/1024), exp2 softmax.
// Vectorized: one short4 load per tensor per thread; packed ushort4 ctx store.
// ---------------------------------------------------------------------------
__global__ __launch_bounds__(256) void k_clip_attn(const unsigned short* __restrict__ qkv,
                                                   unsigned short* __restrict__ ctx)
{
    __shared__ float qs[CS_][65], ks[CS_][65], vs[CS_][65], ps[CS_][17];
    int id = blockIdx.x;
    int h = id & (H_ - 1);
    int n = (id / H_) % NC_;
    int b = id / (H_ * NC_);
    long long base = (((long long)b * NC_ + n) * CS_) * QKVS + h * HD_;
    int tid = threadIdx.x;
    {
        int e = tid << 2;                  // 4 contiguous elems (same row)
        int r = e >> 6, c = e & 63;
        long long ro = base + (long long)r * QKVS + c;
        short4v qv = *(const short4v*)(qkv + ro);
        short4v kv = *(const short4v*)(qkv + ro + 512);
        short4v vv = *(const short4v*)(qkv + ro + 1024);
#pragma unroll
        for (int j = 0; j < 4; j++) {
            qs[r][c + j] = bf2f((unsigned short)qv[j]);
            ks[r][c + j] = bf2f((unsigned short)kv[j]);
            vs[r][c + j] = bf2f((unsigned short)vv[j]);
        }
    }
    __syncthreads();
    int qr = tid >> 4, kc = tid & 15;
    float s = 0.f;
#pragma unroll
    for (int d = 0; d < HD_; d++) s += qs[qr][d] * ks[kc][d];
    float m = s;
#pragma unroll
    for (int off = 1; off < 16; off <<= 1) m = fmaxf(m, __shfl_xor(m, off));
    float e = ex2(s - m);
    float sum = e;
#pragma unroll
    for (int off = 1; off < 16; off <<= 1) sum += __shfl_xor(sum, off);
    ps[qr][kc] = e / sum;
    __syncthreads();
    int dg = (tid & 15) * 4;
    float o0 = 0, o1 = 0, o2 = 0, o3 = 0;
#pragma unroll
    for (int kk = 0; kk < CS_; kk++) {
        float pp = ps[qr][kk];
        o0 += pp * vs[kk][dg + 0];
        o1 += pp * vs[kk][dg + 1];
        o2 += pp * vs[kk][dg + 2];
        o3 += pp * vs[kk][dg + 3];
    }
    long long ob = ((((long long)b * NC_ + n) * CS_) + qr) * D_ + h * HD_ + dg;
    short4v ov;
    ov[0] = (short)f2bf(o0); ov[1] = (short)f2bf(o1);
    ov[2] = (short)f2bf(o2); ov[3] = (short)f2bf(o3);
    *(short4v*)(ctx + ob) = ov;
}

// ---------------------------------------------------------------------------
// Global flash attention (MFMA, exp2 softmax) on fused QKV buffer.
// 512 thr / 8 waves, 128-row q-tile: K/V staged ONCE per kv-tile for all
// 128 q-rows (halves staging + barriers per q-row vs 64-row blocks).
// Per-wave inner code identical to r23/25 proven flash (wave w owns q-rows
// qt*128 + w*16 .. +15). LDS 32KB: Q 16KB (aliased per-wave as P after qf
// load + lgkmcnt(0); each wave's P region overlays ITS OWN Q rows), K 8KB,
// V 8KB -> 4 blocks x 8 waves = 32 waves/CU. Mask only last kv-tile.
// Defer-max (T13, THR=8 log2). XCD swizzle: h = bid&7.
// Tail: q-rows >= L read in-bounds workspace garbage (audited: max 78.5MB
// into the 92MB bQKV region), rows are MFMA-independent, masked at store.
// ---------------------------------------------------------------------------
__global__ __launch_bounds__(512) void k_flash_mfma(
    const unsigned short* __restrict__ qkv,
    unsigned short* __restrict__ out)
{
    __shared__ unsigned short sh[16384];   // 32KB: [0,16K)=Q then P; K 8K; V 8K
    unsigned short* lQ = sh;               // 128x64 Q tile (dead after qf load)
    unsigned short* lK = sh + 8192;
    unsigned short* lV = sh + 12288;
    int bid = blockIdx.x;
    int h  = bid & 7;
    int inner = bid >> 3;
    int qt = inner % NQT2_;
    int b  = inner / NQT2_;
    int tid = threadIdx.x;
    int q0 = qt * 128;
    long long base = (long long)b * L_ * QKVS + h * HD_;

    int w = tid >> 6, lane = tid & 63;     // w in 0..7
    int l15 = lane & 15, lg = lane >> 4;
    int lrow = lane >> 3, lslot = lane & 7;
    int srow = lane;                       // V staging: token 0..63
    int sd0  = w << 3;                     // V staging: d-group of 8 (8 waves)

    // ---- stage Q (128 x 64, swizzled): wave w stages its own 16 rows ----
#pragma unroll
    for (int i = 0; i < 2; i++) {
        int cb = (w << 4) + (i << 3);
        int rr = cb + lrow;
        gload16(qkv + base + (long long)(q0 + rr) * QKVS + ((lslot ^ (rr & 7)) << 3),
                lQ + (cb << 6));
    }
    __syncthreads();

    int qrow = (w << 4) + l15;
    short8 qf[2];
#pragma unroll
    for (int ks = 0; ks < 2; ks++) {
        int slot = (ks << 2) + lg;
        qf[ks] = *(const short8*)(lQ + qrow * 64 + ((slot ^ (qrow & 7)) << 3));
    }
    // each wave's Q reads retired before it crosses the first loop barrier;
    // its P region (below) overlays exactly its own Q rows -> alias safe.
    asm volatile("s_waitcnt lgkmcnt(0)" ::: "memory");
    unsigned short* lPw = lQ + (w << 10);  // per-wave 16x64 P scratch

    float m[4], l[4];
    f32x4 oacc[4];
#pragma unroll
    for (int r = 0; r < 4; r++) { m[r] = -1e30f; l[r] = 0.f; }
#pragma unroll
    for (int nf = 0; nf < 4; nf++) oacc[nf] = (f32x4)0.f;

    for (int kt = 0; kt < NQT_; kt++) {    // 13 kv-tiles of 64
        int k0 = kt * 64;
        __syncthreads();                   // prev iter's lK/lV reads done
        {   // K via gload_lds: wave w stages rows 8w..8w+7 (1 load/thread)
            int rr = (w << 3) + lrow;
            gload16(qkv + base + 512 + (long long)(k0 + rr) * QKVS + ((lslot ^ (rr & 7)) << 3),
                    lK + ((w << 3) << 6));
        }
        {   // V: reg-stage transposed+swizzled, 8 d-cols/thread
            int gr = k0 + srow;
            short8 v0 = (short8)0;
            if (gr < L_) {
                const unsigned short* pv = qkv + base + 1024 + (long long)gr * QKVS + sd0;
                v0 = *(const short8*)pv;
            }
            int ts = srow >> 3, t7 = srow & 7;
#pragma unroll
            for (int i = 0; i < 8; i++) {
                int d = sd0 + i;
                lV[d * 64 + ((ts ^ (d & 7)) << 3) + t7] = (unsigned short)v0[i];
            }
        }
        __syncthreads();

        f32x4 acc[4];
#pragma unroll
        for (int nf = 0; nf < 4; nf++) {
            acc[nf] = (f32x4)0.f;
            int tok = (nf << 4) + l15;
            int key = tok & 7;
#pragma unroll
            for (int ks = 0; ks < 2; ks++) {
                int slot = (ks << 2) + lg;
                short8 kf = *(const short8*)(lK + tok * 64 + ((slot ^ key) << 3));
                acc[nf] = __builtin_amdgcn_mfma_f32_16x16x32_bf16(qf[ks], kf, acc[nf], 0, 0, 0);
            }
        }
        // ---- mask (last kv-tile only: tokens < 768 always valid) ----
        if (kt == NQT_ - 1) {
#pragma unroll
            for (int nf = 0; nf < 4; nf++) {
                bool oob = (k0 + (nf << 4) + l15) >= L_;
#pragma unroll
                for (int r = 0; r < 4; r++)
                    if (oob) acc[nf][r] = -1e30f;
            }
        }
        // ---- row max ----
        float rm[4];
#pragma unroll
        for (int r = 0; r < 4; r++) rm[r] = -1e30f;
#pragma unroll
        for (int nf = 0; nf < 4; nf++) {
#pragma unroll
            for (int r = 0; r < 4; r++) rm[r] = fmaxf(rm[r], acc[nf][r]);
        }
#pragma unroll
        for (int off = 1; off < 16; off <<= 1) {
#pragma unroll
            for (int r = 0; r < 4; r++) rm[r] = fmaxf(rm[r], __shfl_xor(rm[r], off));
        }
        // ---- defer-max (T13): rescale only if some row grew by >8 (log2) ----
        bool need = false;
#pragma unroll
        for (int r = 0; r < 4; r++) need = need || (rm[r] > m[r] + 8.0f);
        if (__ballot(need)) {
#pragma unroll
            for (int r = 0; r < 4; r++) {
                float mn = fmaxf(m[r], rm[r]);
                float sc = ex2(m[r] - mn);
                m[r] = mn;
                l[r] *= sc;
#pragma unroll
                for (int nf = 0; nf < 4; nf++) oacc[nf][r] *= sc;
            }
        }
        // ---- P = exp2(S-m) -> per-wave LDS (bf16) ----
        float ls[4];
#pragma unroll
        for (int r = 0; r < 4; r++) ls[r] = 0.f;
#pragma unroll
        for (int nf = 0; nf < 4; nf++) {
            int tok = (nf << 4) + l15;
            int slot = tok >> 3, t7 = tok & 7;
#pragma unroll
            for (int r = 0; r < 4; r++) {
                float p = ex2(acc[nf][r] - m[r]);
                ls[r] += p;
                int row = (lg << 2) + r;
                lPw[row * 64 + ((slot ^ (row & 7)) << 3) + t7] = f2bf(p);
            }
        }
#pragma unroll
        for (int off = 1; off < 16; off <<= 1) {
#pragma unroll
            for (int r = 0; r < 4; r++) ls[r] += __shfl_xor(ls[r], off);
        }
#pragma unroll
        for (int r = 0; r < 4; r++) l[r] += ls[r];
        // ---- PV (wave-private lPw: in-order DS, no barrier needed) ----
#pragma unroll
        for (int ks = 0; ks < 2; ks++) {
            int slot = (ks << 2) + lg;
            short8 pa = *(const short8*)(lPw + l15 * 64 + ((slot ^ (l15 & 7)) << 3));
#pragma unroll
            for (int nf = 0; nf < 4; nf++) {
                int d = (nf << 4) + l15;
                short8 vb = *(const short8*)(lV + d * 64 + ((slot ^ (d & 7)) << 3));
                oacc[nf] = __builtin_amdgcn_mfma_f32_16x16x32_bf16(pa, vb, oacc[nf], 0, 0, 0);
            }
        }
    }
    long long obase = (long long)b * L_ * D_ + h * HD_;
#pragma unroll
    for (int r = 0; r < 4; r++) {
        int gr = q0 + (w << 4) + (lg << 2) + r;
        if (gr >= L_) continue;
        float inv = 1.f / l[r];
        long long ob = obase + (long long)gr * D_;
#pragma unroll
        for (int nf = 0; nf < 4; nf++)
            out[ob + (nf << 4) + l15] = f2bf(oacc[nf][r] * inv);
    }
}

// ---------------------------------------------------------------------------
// gemm launcher: 1D grid + XCD swizzle, 512 threads. mode 0 iff G>1.
// ---------------------------------------------------------------------------
static inline void gemm(hipStream_t st, const unsigned short* A, const unsigned short* WTp,
                        const float* b0, const float* b1, const float* b2,
                        const float* res, const float* xg, void* C,
                        int M, int N, int K, int ldwk, int G,
                        long long sAb, long long sWb, long long sBb,
                        long long sRb, long long sCb,
                        float alpha, float alpha1, int relu, int biasmode,
                        int resmode, int outbf16)
{
    int NX = N / 128;
    int NY = (M + 127) >> 7;
    int mode = (G > 1) ? 0 : 1;
    int NYp = mode ? ((NY + 7) & ~7) : NY;
    int nblk = mode ? (NYp * NX) : (G * NY * NX);
    k_gemm_mfma<<<nblk, 512, 0, st>>>(A, WTp, b0, b1, b2, res, xg, C,
                                      M, N, K, ldwk, NX, NY, mode,
                                      sAb, sWb, sBb, sRb, sCb,
                                      alpha, alpha1, relu, biasmode, resmode, outbf16);
}

extern "C" void kernel_launch(void* const* d_in, const int* in_sizes, int n_in,
                              void* d_out, int out_size, void* d_ws, size_t ws_size,
                              hipStream_t stream)
{
    (void)in_sizes; (void)n_in; (void)out_size; (void)ws_size;
    const float* x      = (const float*)d_in[0];
    const float* g_ln_g = (const float*)d_in[2];
    const float* g_ln_b = (const float*)d_in[3];
    const float* Wq = (const float*)d_in[4];
    const float* Wk = (const float*)d_in[5];
    const float* Wv = (const float*)d_in[6];
    const float* Wo = (const float*)d_in[7];
    const float* bq = (const float*)d_in[8];
    const float* bk = (const float*)d_in[9];
    const float* bv = (const float*)d_in[10];
    const float* bo = (const float*)d_in[11];
    const float* f_ln_g = (const float*)d_in[12];
    const float* f_ln_b = (const float*)d_in[13];
    const float* W1 = (const float*)d_in[14];
    const float* b1 = (const float*)d_in[15];
    const float* W2 = (const float*)d_in[16];
    const float* b2 = (const float*)d_in[17];
    const float* c_ln_g = (const float*)d_in[18];
    const float* c_ln_b = (const float*)d_in[19];
    const float* cWq = (const float*)d_in[20];
    const float* cWk = (const float*)d_in[21];
    const float* cWv = (const float*)d_in[22];
    const float* cWo = (const float*)d_in[23];
    const float* cbq = (const float*)d_in[24];
    const float* cbk = (const float*)d_in[25];
    const float* cbv = (const float*)d_in[26];
    const float* cbo = (const float*)d_in[27];
    const float* cf_ln_g = (const float*)d_in[28];
    const float* cf_ln_b = (const float*)d_in[29];
    const float* cW1 = (const float*)d_in[30];
    const float* cb1 = (const float*)d_in[31];
    const float* cW2 = (const float*)d_in[32];
    const float* cb2 = (const float*)d_in[33];

    // ---- workspace layout (236 MB) ----
    char* wsb = (char*)d_ws;
    float*          bA   = (float*)wsb;                              // 64MB f32: hcl -> clips_out -> h
    unsigned short* bB   = (unsigned short*)(wsb + (64ll  << 20));   // 32MB bf16 activations
    unsigned short* bQKV = (unsigned short*)(wsb + (96ll  << 20));   // 92MB: fused qkv / fmid chunks
    unsigned short* wT   = (unsigned short*)(wsb + (188ll << 20));   // 48MB: weight transposes

    const long long sA   = (long long)MC_ * D_;
    const long long sQKV = (long long)MC_ * QKVS;
    const long long sWW  = (long long)D_ * D_;
    const int MG = B_ * L_;

    // ================= clip path =================
    k_ln<<<B_ * MC_, 256, 0, stream>>>(x, bB, c_ln_g, c_ln_b, MC_, D_, 2);   // cn (fused gather)
    k_wt_stack<<<dim3(16, 16, 3 * B_), 256, 0, stream>>>(cWq, cWk, cWv, nullptr,
                                                         wT, B_, 3, sWW);
    gemm(stream, bB, wT, cbq, cbk, cbv, nullptr, nullptr, bQKV,
         MC_, QKVS, D_, D_, B_, sA, 3 * sWW, D_, 0, sQKV,
         QS, 1.0f, 0, 3, 0, 1);                                              // fused clip QKV
    k_clip_attn<<<B_ * NC_ * H_, 256, 0, stream>>>(bQKV, bB);                // ctx -> bB
    k_wt<<<dim3(16, 16, B_), 256, 0, stream>>>(cWo, wT, D_, D_, sWW, sWW);
    gemm(stream, bB, wT, cbo, nullptr, nullptr, nullptr, x, bA,
         MC_, D_, D_, D_, B_, sA, sWW, D_, 0, sA,
         1.0f, 1.0f, 0, 1, 2, 0);                                            // hcl f32 -> bA
    k_ln<<<B_ * MC_, 256, 0, stream>>>(bA, bB, cf_ln_g, cf_ln_b, MC_, D_, 0); // fn
    for (int c = 0; c < 2; c++) {   // clip FFN, 2 chunks of 1024
        k_wt<<<dim3(32, 16, B_), 256, 0, stream>>>(cW1 + c * 1024, wT, FF_, D_,
                                                   (long long)D_ * FF_, 1024ll * D_);
        gemm(stream, bB, wT, cb1 + c * 1024, nullptr, nullptr, nullptr, nullptr, bQKV,
             MC_, 1024, D_, D_, B_, sA, 1024ll * D_, FF_, 0, (long long)MC_ * 1024,
             1.0f, 1.0f, 1, 1, 0, 1);                                        // fmid chunk (relu)
        k_wt<<<dim3(16, 32, B_), 256, 0, stream>>>(cW2 + (long long)c * 1024 * D_, wT,
                                                   D_, 1024, (long long)FF_ * D_,
                                                   (long long)D_ * 1024);
        gemm(stream, bQKV, wT, cb2, nullptr, nullptr, bA, nullptr, bA,
             MC_, D_, 1024, 1024, B_, (long long)MC_ * 1024, (long long)D_ * 1024,
             D_, sA, sA, 1.0f, 1.0f, 0, (c == 0) ? 1 : 0, 1, 0);             // clips_out in-place bA
    }

    // ================= global path =================
    unsigned short* gQKVO = wT;                    // [2048][512]
    unsigned short* gW1   = wT + 4 * 262144;       // [2048][512]
    unsigned short* gW2   = wT + 8 * 262144;       // [512][2048]
    k_wt_stack<<<dim3(16, 16, 4), 256, 0, stream>>>(Wq, Wk, Wv, Wo, gQKVO, 1, 4, 0);
    k_wt<<<dim3(64, 16, 1), 256, 0, stream>>>(W1, gW1, FF_, D_, 0, 0);
    k_wt<<<dim3(16, 64, 1), 256, 0, stream>>>(W2, gW2, D_, FF_, 0, 0);

    k_ln<<<MG, 256, 0, stream>>>(bA, bB, g_ln_g, g_ln_b, L_, 0, 1);          // xn (x_rec gather)
    gemm(stream, bB, gQKVO, bq, bk, bv, nullptr, nullptr, bQKV,
         MG, QKVS, D_, D_, 1, 0, 0, 0, 0, 0,
         QS, 1.0f, 0, 3, 0, 1);                                              // fused global QKV
    k_flash_mfma<<<B_ * H_ * NQT2_, 512, 0, stream>>>(bQKV, bB);             // ctx2 -> bB
    gemm(stream, bB, gQKVO + 3 * 262144, bo, nullptr, nullptr, x, nullptr, bA,
         MG, D_, D_, D_, 1, 0, 0, 0, 0, 0,
         1.0f, 1.0f, 0, 1, 1, 0);                                            // h f32 -> bA (res=x)
    k_ln<<<MG, 256, 0, stream>>>(bA, bB, f_ln_g, f_ln_b, MG, 0, 0);          // hn
    for (int c = 0; c < 2; c++) {    // global FFN, 2 chunks of 1024
        gemm(stream, bB, gW1 + (long long)c * 1024 * 512, b1 + c * 1024,
             nullptr, nullptr, nullptr, nullptr, bQKV,
             MG, 1024, D_, D_, 1, 0, 0, 0, 0, 0,
             1.0f, 1.0f, 1, 1, 0, 1);                                        // mid2 chunk (relu)
        gemm(stream, bQKV, gW2 + c * 1024, b2, nullptr, nullptr,
             (c == 0) ? bA : (float*)d_out, nullptr, d_out,
             MG, D_, 1024, FF_, 1, 0, 0, 0, 0, 0,
             1.0f, 1.0f, 0, (c == 0) ? 1 : 0, 1, 0);                         // out (in-place c=1)
    }
}

// Round 27
// 1376.862 us; speedup vs baseline: 1.0041x; 1.0026x over previous
//
#include <hip/hip_runtime.h>

#define B_   32
#define L_   796
#define D_   512
#define H_   8
#define HD_  64
#define FF_  2048
#define CS_  16
#define STR_ 13
#define NC_  61
#define NQT_ 13             // kv-tiles of 64
#define NQT2_ 7             // q-tiles of 128 rows (ceil(796/128))
#define MC_  976            // NC_*CS_ rows per batch (clip path)
#define QKVS 1536           // fused QKV row stride
#define QS   (0.125f * 1.44269504f)   // 1/sqrt(64) * log2(e)  -> exp2 softmax

typedef __attribute__((ext_vector_type(8))) short short8;
typedef __attribute__((ext_vector_type(4))) short short4v;
typedef __attribute__((ext_vector_type(4))) float f32x4;

__device__ __forceinline__ unsigned short f2bf(float x) {
    unsigned u = __float_as_uint(x);
    unsigned r = u + 0x7FFFu + ((u >> 16) & 1u);   // RNE
    return (unsigned short)(r >> 16);
}
__device__ __forceinline__ float bf2f(unsigned short h) {
    return __uint_as_float(((unsigned)h) << 16);
}
__device__ __forceinline__ float ex2(float x) {      // native v_exp_f32 (2^x)
    return __builtin_amdgcn_exp2f(x);
}
__device__ __forceinline__ void gload16(const unsigned short* g, unsigned short* l) {
    __builtin_amdgcn_global_load_lds(
        (const __attribute__((address_space(1))) void*)g,
        (__attribute__((address_space(3))) void*)l, 16, 0, 0);
}

// ---------------------------------------------------------------------------
// LayerNorm D=512, f32 in -> bf16 out.
// gather=0: direct rows; gather=1: x_rec remap; gather=2: clip build from x.
// ---------------------------------------------------------------------------
__global__ __launch_bounds__(256) void k_ln(const float* __restrict__ in,
                                            unsigned short* __restrict__ out,
                                            const float* __restrict__ gamma,
                                            const float* __restrict__ beta,
                                            int rows_per_batch, int gstride, int gather)
{
    __shared__ float red[8];
    long long row = blockIdx.x;
    int tid = threadIdx.x;
    int b;
    float v0, v1;
    if (gather == 2) {
        b = (int)(row / MC_);
        int rr = (int)(row % MC_);
        int n = rr >> 4, c = rr & 15;
        long long xb = (long long)b * L_ * D_;
        int d0 = tid, st0, sd0;
        if (d0 < 128) { st0 = n * STR_ + c; sd0 = d0; }
        else { int j = d0 - 128; st0 = n * STR_ + (j & 15); sd0 = 128 + ((j >> 4) << 4) + c; }
        v0 = in[xb + (long long)st0 * D_ + sd0];
        int j1 = tid + 128;                 // (tid+256)-128
        int st1 = n * STR_ + (j1 & 15), sd1 = 128 + ((j1 >> 4) << 4) + c;
        v1 = in[xb + (long long)st1 * D_ + sd1];
    } else {
        long long srow = row;
        if (gather == 1) {
            int p = (int)(row % L_);
            b = (int)(row / L_);
            int ci = p / STR_; if (ci > NC_ - 1) ci = NC_ - 1;
            srow = ((long long)b * NC_ + ci) * CS_ + (p - ci * STR_);
        } else {
            b = (int)(row / rows_per_batch);
        }
        const float* xr = in + srow * D_;
        v0 = xr[tid]; v1 = xr[tid + 256];
    }
    float s = v0 + v1;
#pragma unroll
    for (int off = 1; off < 64; off <<= 1) s += __shfl_xor(s, off);
    if ((tid & 63) == 0) red[tid >> 6] = s;
    __syncthreads();
    float mean = (red[0] + red[1] + red[2] + red[3]) * (1.0f / 512.0f);
    float d0 = v0 - mean, d1 = v1 - mean;
    float vv = d0 * d0 + d1 * d1;
#pragma unroll
    for (int off = 1; off < 64; off <<= 1) vv += __shfl_xor(vv, off);
    if ((tid & 63) == 0) red[4 + (tid >> 6)] = vv;
    __syncthreads();
    float var = (red[4] + red[5] + red[6] + red[7]) * (1.0f / 512.0f);
    float rstd = rsqrtf(var + 1e-6f);
    const float* g  = gamma + (long long)b * gstride;
    const float* bt = beta  + (long long)b * gstride;
    unsigned short* o = out + row * D_;
    o[tid]       = f2bf(d0 * rstd * g[tid]       + bt[tid]);
    o[tid + 256] = f2bf(d1 * rstd * g[tid + 256] + bt[tid + 256]);
}

// ---------------------------------------------------------------------------
// Weight transpose+convert: W f32 [K x N] (row stride rowStride) -> T bf16
// [N][K] (row stride tStride). grid (N/32, K/32, G).
// ---------------------------------------------------------------------------
__global__ __launch_bounds__(256) void k_wt(const float* __restrict__ W,
                                            unsigned short* __restrict__ T,
                                            int rowStride, int tStride,
                                            long long sWb, long long sTb)
{
    __shared__ float t[32][33];
    int z = blockIdx.z;
    const float* Wz = W + (long long)z * sWb;
    unsigned short* Tz = T + (long long)z * sTb;
    int n0 = blockIdx.x << 5, k0 = blockIdx.y << 5;
    int tx = threadIdx.x & 31, ty = threadIdx.x >> 5;
#pragma unroll
    for (int i = 0; i < 4; i++) {
        int k = ty + (i << 3);
        t[k][tx] = Wz[(long long)(k0 + k) * rowStride + n0 + tx];
    }
    __syncthreads();
#pragma unroll
    for (int i = 0; i < 4; i++) {
        int n = ty + (i << 3);
        Tz[(long long)(n0 + n) * tStride + k0 + tx] = f2bf(t[tx][n]);
    }
}

// Stacked transpose of up to 4 square 512x512 tensors x nb batches.
// z = tensor*nb + batch. dst: [batch][tensor*512 + n][512].
__global__ __launch_bounds__(256) void k_wt_stack(const float* __restrict__ Wa,
                                                  const float* __restrict__ Wb,
                                                  const float* __restrict__ Wc,
                                                  const float* __restrict__ Wd,
                                                  unsigned short* __restrict__ T,
                                                  int nb, int ntens, long long sWb)
{
    __shared__ float t[32][33];
    int z = blockIdx.z;
    int tt = z / nb, b = z % nb;
    const float* Wz = (tt == 0 ? Wa : tt == 1 ? Wb : tt == 2 ? Wc : Wd)
                      + (long long)b * sWb;
    unsigned short* Tz = T + ((long long)b * ntens + tt) * (512 * 512);
    int n0 = blockIdx.x << 5, k0 = blockIdx.y << 5;
    int tx = threadIdx.x & 31, ty = threadIdx.x >> 5;
#pragma unroll
    for (int i = 0; i < 4; i++) {
        int k = ty + (i << 3);
        t[k][tx] = Wz[(long long)(k0 + k) * 512 + n0 + tx];
    }
    __syncthreads();
#pragma unroll
    for (int i = 0; i < 4; i++) {
        int n = ty + (i << 3);
        Tz[(long long)(n0 + n) * 512 + k0 + tx] = f2bf(t[tx][n]);
    }
}

// ---------------------------------------------------------------------------
// bf16 MFMA GEMM — counted-vmcnt pipeline (round-12 skeleton), BK=32,
// 512 thr / 8 waves (2M x 4N, each wave 64x32 out) — round-21/23/25 proven.
// NOTE: no min-waves clause (r22: forcing 8 waves/EU spilled VGPR 80->32).
// Swizzle key (r>>1)&3 (conflict-free, r20-verified: 0 conflicts).
// ---------------------------------------------------------------------------
__global__ __launch_bounds__(512) void k_gemm_mfma(
    const unsigned short* __restrict__ A, const unsigned short* __restrict__ WT,
    const float* __restrict__ b0p, const float* __restrict__ b1p,
    const float* __restrict__ b2p,
    const float* res, const float* __restrict__ xg, void* Cout,
    int M, int N, int K, int ldwk, int NX, int NYd, int mode,
    long long sAb, long long sWb, long long sBb, long long sRb, long long sCb,
    float alpha, float alpha1, int relu, int biasmode, int resmode, int outbf16)
{
    __shared__ unsigned short lds[16384];      // 32 KB: 2 x (A 8KB + W 8KB)
    int tid = threadIdx.x;

    // ---- XCD-aware decode ----
    int bid = blockIdx.x;
    int xcd = bid & 7, inner = bid >> 3;
    int x = inner % NX, t = inner / NX;
    int y, z;
    if (mode == 0) { y = t % NYd; z = (t / NYd) * 8 + xcd; }
    else           { y = t * 8 + xcd; z = 0; }
    int row0 = y << 7, col0 = x << 7;
    if (row0 >= M) return;                 // padded row-tile (mode 1)

    const unsigned short* Ab = A + z * sAb;
    const unsigned short* Wb = WT + z * sWb;

    int w = tid >> 6, lane = tid & 63;
    int wr = (w >> 2) << 6;                // 0 / 64
    int wc = (w & 3) << 5;                 // 0 / 32 / 64 / 96
    int l15 = lane & 15, lg = lane >> 4;   // lg in 0..3 = K-slot of 32
    int lrow4 = lane >> 2, lslot = lane & 3;   // staging: 16 rows x 4 slots/wave

    f32x4 acc[4][2];
#pragma unroll
    for (int i = 0; i < 4; i++)
#pragma unroll
        for (int j = 0; j < 2; j++) acc[i][j] = (f32x4)0.f;

    const int nt = K >> 5;                     // BK = 32
    int srow = (w << 4) + lrow4;               // staging row (wave w: rows w*16..+15)
    int skey = (srow >> 1) & 3;

    // ---- prologue: stage tile 0 -> buf0, tile 1 -> buf1 ----
#pragma unroll
    for (int pt = 0; pt < 2; ++pt) {
        int k0 = pt << 5;
        unsigned short* sA = lds + (pt << 13);
        unsigned short* sW = sA + 4096;
        gload16(Ab + (long long)(row0 + srow) * K + k0 + ((lslot ^ skey) << 3),
                sA + ((w << 4) << 5));
        gload16(Wb + (long long)(col0 + srow) * ldwk + k0 + ((lslot ^ skey) << 3),
                sW + ((w << 4) << 5));
    }

    for (int kt = 0; kt < nt; ++kt) {
        // (1) counted wait: tile kt's 2 loads landed; tile kt+1's stay in flight
        if (kt + 1 < nt) asm volatile("s_waitcnt vmcnt(2)" ::: "memory");
        else             asm volatile("s_waitcnt vmcnt(0)" ::: "memory");
        __builtin_amdgcn_s_barrier();      // all waves' tile-kt loads landed

        unsigned short* lA = lds + ((kt & 1) << 13);
        unsigned short* lW = lA + 4096;

        // (2) ds_read fragments of current buffer (slot = lg ^ key)
        short8 af[4], bfr[2];
#pragma unroll
        for (int mf = 0; mf < 4; mf++) {
            int r = wr + (mf << 4) + l15;
            af[mf] = *(const short8*)(lA + (r << 5) + ((lg ^ ((r >> 1) & 3)) << 3));
        }
#pragma unroll
        for (int nf = 0; nf < 2; nf++) {
            int r = wc + (nf << 4) + l15;
            bfr[nf] = *(const short8*)(lW + (r << 5) + ((lg ^ ((r >> 1) & 3)) << 3));
        }

        // (3) own reads retired -> all-waves barrier (raw: no vmcnt drain!)
        asm volatile("s_waitcnt lgkmcnt(0)" ::: "memory");
        __builtin_amdgcn_s_barrier();

        // (4) stage tile kt+2 into the buffer just consumed (now safe)
        if (kt + 2 < nt) {
            int k0 = (kt + 2) << 5;
            gload16(Ab + (long long)(row0 + srow) * K + k0 + ((lslot ^ skey) << 3),
                    lA + ((w << 4) << 5));
            gload16(Wb + (long long)(col0 + srow) * ldwk + k0 + ((lslot ^ skey) << 3),
                    lW + ((w << 4) << 5));
        }

        // (5) register-only MFMA cluster
        __builtin_amdgcn_s_setprio(1);
#pragma unroll
        for (int mf = 0; mf < 4; mf++)
#pragma unroll
            for (int nf = 0; nf < 2; nf++)
                acc[mf][nf] = __builtin_amdgcn_mfma_f32_16x16x32_bf16(
                    af[mf], bfr[nf], acc[mf][nf], 0, 0, 0);
        __builtin_amdgcn_s_setprio(0);
    }

#pragma unroll
    for (int mf = 0; mf < 4; mf++) {
#pragma unroll
        for (int reg = 0; reg < 4; reg++) {
            int gr = row0 + wr + (mf << 4) + (lg << 2) + reg;
            if (gr >= M) continue;
#pragma unroll
            for (int nf = 0; nf < 2; nf++) {
                int gc = col0 + wc + (nf << 4) + l15;
                float v = acc[mf][nf][reg];
                if (biasmode == 1) v += b0p[z * sBb + gc];
                else if (biasmode == 3) {
                    const float* bp = gc < 512 ? b0p : (gc < 1024 ? b1p : b2p);
                    v += bp[z * sBb + (gc & 511)];
                }
                v *= (gc < 512) ? alpha : alpha1;
                if (relu) v = fmaxf(v, 0.f);
                if (resmode == 1) {
                    v += res[z * sRb + (long long)gr * N + gc];
                } else if (resmode == 2) {
                    int n = gr >> 4, c = gr & 15;
                    int st, sd;
                    if (gc < 128) { st = n * STR_ + c; sd = gc; }
                    else {
                        int jj = gc - 128;
                        st = n * STR_ + (jj & 15);
                        sd = 128 + ((jj >> 4) << 4) + c;
                    }
                    v += xg[((long long)z * L_ + st) * D_ + sd];
                }
                long long co = z * sCb + (long long)gr * N + gc;
                if (outbf16) ((unsigned short*)Cout)[co] = f2bf(v);
                else         ((float*)Cout)[co] = v;
            }
        }
    }
}

// ---------------------------------------------------------------------------
// Clip attention on fused QKV (stride QKVS, offsets 0/512/1024), exp2 softmax.
// Vectorized: one short4 load per tensor per thread; packed ushort4 ctx store.
// ---------------------------------------------------------------------------
__global__ __launch_bounds__(256) void k_clip_attn(const unsigned short* __restrict__ qkv,
                                                   unsigned short* __restrict__ ctx)
{
    __shared__ float qs[CS_][65], ks[CS_][65], vs[CS_][65], ps[CS_][17];
    int id = blockIdx.x;
    int h = id & (H_ - 1);
    int n = (id / H_) % NC_;
    int b = id / (H_ * NC_);
    long long base = (((long long)b * NC_ + n) * CS_) * QKVS + h * HD_;
    int tid = threadIdx.x;
    {
        int e = tid << 2;                  // 4 contiguous elems (same row)
        int r = e >> 6, c = e & 63;
        long long ro = base + (long long)r * QKVS + c;
        short4v qv = *(const short4v*)(qkv + ro);
        short4v kv = *(const short4v*)(qkv + ro + 512);
        short4v vv = *(const short4v*)(qkv + ro + 1024);
#pragma unroll
        for (int j = 0; j < 4; j++) {
            qs[r][c + j] = bf2f((unsigned short)qv[j]);
            ks[r][c + j] = bf2f((unsigned short)kv[j]);
            vs[r][c + j] = bf2f((unsigned short)vv[j]);
        }
    }
    __syncthreads();
    int qr = tid >> 4, kc = tid & 15;
    float s = 0.f;
#pragma unroll
    for (int d = 0; d < HD_; d++) s += qs[qr][d] * ks[kc][d];
    float m = s;
#pragma unroll
    for (int off = 1; off < 16; off <<= 1) m = fmaxf(m, __shfl_xor(m, off));
    float e = ex2(s - m);
    float sum = e;
#pragma unroll
    for (int off = 1; off < 16; off <<= 1) sum += __shfl_xor(sum, off);
    ps[qr][kc] = e / sum;
    __syncthreads();
    int dg = (tid & 15) * 4;
    float o0 = 0, o1 = 0, o2 = 0, o3 = 0;
#pragma unroll
    for (int kk = 0; kk < CS_; kk++) {
        float pp = ps[qr][kk];
        o0 += pp * vs[kk][dg + 0];
        o1 += pp * vs[kk][dg + 1];
        o2 += pp * vs[kk][dg + 2];
        o3 += pp * vs[kk][dg + 3];
    }
    long long ob = ((((long long)b * NC_ + n) * CS_) + qr) * D_ + h * HD_ + dg;
    short4v ov;
    ov[0] = (short)f2bf(o0); ov[1] = (short)f2bf(o1);
    ov[2] = (short)f2bf(o2); ov[3] = (short)f2bf(o3);
    *(short4v*)(ctx + ob) = ov;
}

// ---------------------------------------------------------------------------
// Global flash attention (MFMA, exp2 softmax) on fused QKV buffer.
// 512 thr / 8 waves, 128-row q-tile, K/V DOUBLE-BUFFERED: ONE barrier per
// kv-tile (vs 2), next-tile K gload_lds + V global->reg issued right after
// QK^T so HBM latency hides under softmax+PV (GEMM r12 pipeline argument
// transplanted: buffer `nxt` last read in iter kt-1 which ended before
// bar(kt); all writes to it issued after bar(kt); __syncthreads drains
// vmcnt per HIP semantics -> K(kt) visible at bar; in-order vmcnt means the
// V-reg dep wait also retires the older K gload).
// LDS 48KB: Q/P 16K (per-wave P overlays own Q rows after qf+lgkmcnt(0)),
// K dbuf 2x8K, V dbuf 2x8K -> 3 blocks x 8 waves = 24 waves/CU.
// Mask only last kv-tile. Defer-max (T13). XCD swizzle: h = bid&7.
// ---------------------------------------------------------------------------
__global__ __launch_bounds__(512) void k_flash_mfma(
    const unsigned short* __restrict__ qkv,
    unsigned short* __restrict__ out)
{
    __shared__ unsigned short sh[24576];   // 48KB
    unsigned short* lQ  = sh;              // 128x64 Q tile (dead after qf load)
    unsigned short* lKb = sh + 8192;       // K double buffer (2 x 64x64)
    unsigned short* lVb = sh + 16384;      // V double buffer (2 x 64x64, transposed)
    int bid = blockIdx.x;
    int h  = bid & 7;
    int inner = bid >> 3;
    int qt = inner % NQT2_;
    int b  = inner / NQT2_;
    int tid = threadIdx.x;
    int q0 = qt * 128;
    long long base = (long long)b * L_ * QKVS + h * HD_;

    int w = tid >> 6, lane = tid & 63;     // w in 0..7
    int l15 = lane & 15, lg = lane >> 4;
    int lrow = lane >> 3, lslot = lane & 7;
    int srow = lane;                       // V staging: token 0..63
    int sd0  = w << 3;                     // V staging: d-group of 8 (8 waves)

    // ---- prologue: stage Q; issue K(0) gload; V(0) -> regs ----
#pragma unroll
    for (int i = 0; i < 2; i++) {
        int cb = (w << 4) + (i << 3);
        int rr = cb + lrow;
        gload16(qkv + base + (long long)(q0 + rr) * QKVS + ((lslot ^ (rr & 7)) << 3),
                lQ + (cb << 6));
    }
    {
        int rr = (w << 3) + lrow;
        gload16(qkv + base + 512 + (long long)rr * QKVS + ((lslot ^ (rr & 7)) << 3),
                lKb + ((w << 3) << 6));
    }
    short8 vreg = *(const short8*)(qkv + base + 1024 + (long long)srow * QKVS + sd0);
    __syncthreads();                       // Q + K(0) in LDS (vmcnt drained)

    int qrow = (w << 4) + l15;
    short8 qf[2];
#pragma unroll
    for (int ks = 0; ks < 2; ks++) {
        int slot = (ks << 2) + lg;
        qf[ks] = *(const short8*)(lQ + qrow * 64 + ((slot ^ (qrow & 7)) << 3));
    }
    // each wave's Q reads retired before it crosses the first loop barrier;
    // its P region (below) overlays exactly its own Q rows -> alias safe.
    asm volatile("s_waitcnt lgkmcnt(0)" ::: "memory");
    unsigned short* lPw = lQ + (w << 10);  // per-wave 16x64 P scratch

    float m[4], l[4];
    f32x4 oacc[4];
#pragma unroll
    for (int r = 0; r < 4; r++) { m[r] = -1e30f; l[r] = 0.f; }
#pragma unroll
    for (int nf = 0; nf < 4; nf++) oacc[nf] = (f32x4)0.f;

    int ts = srow >> 3, t7 = srow & 7;
    for (int kt = 0; kt < NQT_; kt++) {    // 13 kv-tiles of 64
        int k0 = kt * 64;
        unsigned short* lK = lKb + ((kt & 1) << 12);
        unsigned short* lV = lVb + ((kt & 1) << 12);
        // ---- ds_write V(kt) from regs (transposed + swizzled) ----
#pragma unroll
        for (int i = 0; i < 8; i++) {
            int d = sd0 + i;
            lV[d * 64 + ((ts ^ (d & 7)) << 3) + t7] = (unsigned short)vreg[i];
        }
        __syncthreads();   // drains vmcnt+lgkm: K(kt) in LDS, V(kt) writes visible

        // ---- QK^T from lK[cur] ----
        f32x4 acc[4];
#pragma unroll
        for (int nf = 0; nf < 4; nf++) {
            acc[nf] = (f32x4)0.f;
            int tok = (nf << 4) + l15;
            int key = tok & 7;
#pragma unroll
            for (int ks = 0; ks < 2; ks++) {
                int slot = (ks << 2) + lg;
                short8 kf = *(const short8*)(lK + tok * 64 + ((slot ^ key) << 3));
                acc[nf] = __builtin_amdgcn_mfma_f32_16x16x32_bf16(qf[ks], kf, acc[nf], 0, 0, 0);
            }
        }
        // ---- issue next-tile loads into the OTHER buffers (latency hides
        //      under softmax + PV; consumed only after the next barrier) ----
        if (kt + 1 < NQT_) {
            int k0n = (kt + 1) << 6;
            int rr = (w << 3) + lrow;
            gload16(qkv + base + 512 + (long long)(k0n + rr) * QKVS + ((lslot ^ (rr & 7)) << 3),
                    lKb + (((kt + 1) & 1) << 12) + ((w << 3) << 6));
            int grn = k0n + srow;
            vreg = (short8)0;
            if (grn < L_)
                vreg = *(const short8*)(qkv + base + 1024 + (long long)grn * QKVS + sd0);
        }
        // ---- mask (last kv-tile only: tokens < 768 always valid) ----
        if (kt == NQT_ - 1) {
#pragma unroll
            for (int nf = 0; nf < 4; nf++) {
                bool oob = (k0 + (nf << 4) + l15) >= L_;
#pragma unroll
                for (int r = 0; r < 4; r++)
                    if (oob) acc[nf][r] = -1e30f;
            }
        }
        // ---- row max ----
        float rm[4];
#pragma unroll
        for (int r = 0; r < 4; r++) rm[r] = -1e30f;
#pragma unroll
        for (int nf = 0; nf < 4; nf++) {
#pragma unroll
            for (int r = 0; r < 4; r++) rm[r] = fmaxf(rm[r], acc[nf][r]);
        }
#pragma unroll
        for (int off = 1; off < 16; off <<= 1) {
#pragma unroll
            for (int r = 0; r < 4; r++) rm[r] = fmaxf(rm[r], __shfl_xor(rm[r], off));
        }
        // ---- defer-max (T13): rescale only if some row grew by >8 (log2) ----
        bool need = false;
#pragma unroll
        for (int r = 0; r < 4; r++) need = need || (rm[r] > m[r] + 8.0f);
        if (__ballot(need)) {
#pragma unroll
            for (int r = 0; r < 4; r++) {
                float mn = fmaxf(m[r], rm[r]);
                float sc = ex2(m[r] - mn);
                m[r] = mn;
                l[r] *= sc;
#pragma unroll
                for (int nf = 0; nf < 4; nf++) oacc[nf][r] *= sc;
            }
        }
        // ---- P = exp2(S-m) -> per-wave LDS (bf16) ----
        float ls[4];
#pragma unroll
        for (int r = 0; r < 4; r++) ls[r] = 0.f;
#pragma unroll
        for (int nf = 0; nf < 4; nf++) {
            int tok = (nf << 4) + l15;
            int slot = tok >> 3, tt7 = tok & 7;
#pragma unroll
            for (int r = 0; r < 4; r++) {
                float p = ex2(acc[nf][r] - m[r]);
                ls[r] += p;
                int row = (lg << 2) + r;
                lPw[row * 64 + ((slot ^ (row & 7)) << 3) + tt7] = f2bf(p);
            }
        }
#pragma unroll
        for (int off = 1; off < 16; off <<= 1) {
#pragma unroll
            for (int r = 0; r < 4; r++) ls[r] += __shfl_xor(ls[r], off);
        }
#pragma unroll
        for (int r = 0; r < 4; r++) l[r] += ls[r];
        // ---- PV (wave-private lPw: in-order DS, no barrier needed) ----
#pragma unroll
        for (int ks = 0; ks < 2; ks++) {
            int slot = (ks << 2) + lg;
            short8 pa = *(const short8*)(lPw + l15 * 64 + ((slot ^ (l15 & 7)) << 3));
#pragma unroll
            for (int nf = 0; nf < 4; nf++) {
                int d = (nf << 4) + l15;
                short8 vb = *(const short8*)(lV + d * 64 + ((slot ^ (d & 7)) << 3));
                oacc[nf] = __builtin_amdgcn_mfma_f32_16x16x32_bf16(pa, vb, oacc[nf], 0, 0, 0);
            }
        }
    }
    long long obase = (long long)b * L_ * D_ + h * HD_;
#pragma unroll
    for (int r = 0; r < 4; r++) {
        int gr = q0 + (w << 4) + (lg << 2) + r;
        if (gr >= L_) continue;
        float inv = 1.f / l[r];
        long long ob = obase + (long long)gr * D_;
#pragma unroll
        for (int nf = 0; nf < 4; nf++)
            out[ob + (nf << 4) + l15] = f2bf(oacc[nf][r] * inv);
    }
}

// ---------------------------------------------------------------------------
// gemm launcher: 1D grid + XCD swizzle, 512 threads. mode 0 iff G>1.
// ---------------------------------------------------------------------------
static inline void gemm(hipStream_t st, const unsigned short* A, const unsigned short* WTp,
                        const float* b0, const float* b1, const float* b2,
                        const float* res, const float* xg, void* C,
                        int M, int N, int K, int ldwk, int G,
                        long long sAb, long long sWb, long long sBb,
                        long long sRb, long long sCb,
                        float alpha, float alpha1, int relu, int biasmode,
                        int resmode, int outbf16)
{
    int NX = N / 128;
    int NY = (M + 127) >> 7;
    int mode = (G > 1) ? 0 : 1;
    int NYp = mode ? ((NY + 7) & ~7) : NY;
    int nblk = mode ? (NYp * NX) : (G * NY * NX);
    k_gemm_mfma<<<nblk, 512, 0, st>>>(A, WTp, b0, b1, b2, res, xg, C,
                                      M, N, K, ldwk, NX, NY, mode,
                                      sAb, sWb, sBb, sRb, sCb,
                                      alpha, alpha1, relu, biasmode, resmode, outbf16);
}

extern "C" void kernel_launch(void* const* d_in, const int* in_sizes, int n_in,
                              void* d_out, int out_size, void* d_ws, size_t ws_size,
                              hipStream_t stream)
{
    (void)in_sizes; (void)n_in; (void)out_size; (void)ws_size;
    const float* x      = (const float*)d_in[0];
    const float* g_ln_g = (const float*)d_in[2];
    const float* g_ln_b = (const float*)d_in[3];
    const float* Wq = (const float*)d_in[4];
    const float* Wk = (const float*)d_in[5];
    const float* Wv = (const float*)d_in[6];
    const float* Wo = (const float*)d_in[7];
    const float* bq = (const float*)d_in[8];
    const float* bk = (const float*)d_in[9];
    const float* bv = (const float*)d_in[10];
    const float* bo = (const float*)d_in[11];
    const float* f_ln_g = (const float*)d_in[12];
    const float* f_ln_b = (const float*)d_in[13];
    const float* W1 = (const float*)d_in[14];
    const float* b1 = (const float*)d_in[15];
    const float* W2 = (const float*)d_in[16];
    const float* b2 = (const float*)d_in[17];
    const float* c_ln_g = (const float*)d_in[18];
    const float* c_ln_b = (const float*)d_in[19];
    const float* cWq = (const float*)d_in[20];
    const float* cWk = (const float*)d_in[21];
    const float* cWv = (const float*)d_in[22];
    const float* cWo = (const float*)d_in[23];
    const float* cbq = (const float*)d_in[24];
    const float* cbk = (const float*)d_in[25];
    const float* cbv = (const float*)d_in[26];
    const float* cbo = (const float*)d_in[27];
    const float* cf_ln_g = (const float*)d_in[28];
    const float* cf_ln_b = (const float*)d_in[29];
    const float* cW1 = (const float*)d_in[30];
    const float* cb1 = (const float*)d_in[31];
    const float* cW2 = (const float*)d_in[32];
    const float* cb2 = (const float*)d_in[33];

    // ---- workspace layout (236 MB) ----
    char* wsb = (char*)d_ws;
    float*          bA   = (float*)wsb;                              // 64MB f32: hcl -> clips_out -> h
    unsigned short* bB   = (unsigned short*)(wsb + (64ll  << 20));   // 32MB bf16 activations
    unsigned short* bQKV = (unsigned short*)(wsb + (96ll  << 20));   // 92MB: fused qkv / fmid chunks
    unsigned short* wT   = (unsigned short*)(wsb + (188ll << 20));   // 48MB: weight transposes

    const long long sA   = (long long)MC_ * D_;
    const long long sQKV = (long long)MC_ * QKVS;
    const long long sWW  = (long long)D_ * D_;
    const int MG = B_ * L_;

    // ================= clip path =================
    k_ln<<<B_ * MC_, 256, 0, stream>>>(x, bB, c_ln_g, c_ln_b, MC_, D_, 2);   // cn (fused gather)
    k_wt_stack<<<dim3(16, 16, 3 * B_), 256, 0, stream>>>(cWq, cWk, cWv, nullptr,
                                                         wT, B_, 3, sWW);
    gemm(stream, bB, wT, cbq, cbk, cbv, nullptr, nullptr, bQKV,
         MC_, QKVS, D_, D_, B_, sA, 3 * sWW, D_, 0, sQKV,
         QS, 1.0f, 0, 3, 0, 1);                                              // fused clip QKV
    k_clip_attn<<<B_ * NC_ * H_, 256, 0, stream>>>(bQKV, bB);                // ctx -> bB
    k_wt<<<dim3(16, 16, B_), 256, 0, stream>>>(cWo, wT, D_, D_, sWW, sWW);
    gemm(stream, bB, wT, cbo, nullptr, nullptr, nullptr, x, bA,
         MC_, D_, D_, D_, B_, sA, sWW, D_, 0, sA,
         1.0f, 1.0f, 0, 1, 2, 0);                                            // hcl f32 -> bA
    k_ln<<<B_ * MC_, 256, 0, stream>>>(bA, bB, cf_ln_g, cf_ln_b, MC_, D_, 0); // fn
    for (int c = 0; c < 2; c++) {   // clip FFN, 2 chunks of 1024
        k_wt<<<dim3(32, 16, B_), 256, 0, stream>>>(cW1 + c * 1024, wT, FF_, D_,
                                                   (long long)D_ * FF_, 1024ll * D_);
        gemm(stream, bB, wT, cb1 + c * 1024, nullptr, nullptr, nullptr, nullptr, bQKV,
             MC_, 1024, D_, D_, B_, sA, 1024ll * D_, FF_, 0, (long long)MC_ * 1024,
             1.0f, 1.0f, 1, 1, 0, 1);                                        // fmid chunk (relu)
        k_wt<<<dim3(16, 32, B_), 256, 0, stream>>>(cW2 + (long long)c * 1024 * D_, wT,
                                                   D_, 1024, (long long)FF_ * D_,
                                                   (long long)D_ * 1024);
        gemm(stream, bQKV, wT, cb2, nullptr, nullptr, bA, nullptr, bA,
             MC_, D_, 1024, 1024, B_, (long long)MC_ * 1024, (long long)D_ * 1024,
             D_, sA, sA, 1.0f, 1.0f, 0, (c == 0) ? 1 : 0, 1, 0);             // clips_out in-place bA
    }

    // ================= global path =================
    unsigned short* gQKVO = wT;                    // [2048][512]
    unsigned short* gW1   = wT + 4 * 262144;       // [2048][512]
    unsigned short* gW2   = wT + 8 * 262144;       // [512][2048]
    k_wt_stack<<<dim3(16, 16, 4), 256, 0, stream>>>(Wq, Wk, Wv, Wo, gQKVO, 1, 4, 0);
    k_wt<<<dim3(64, 16, 1), 256, 0, stream>>>(W1, gW1, FF_, D_, 0, 0);
    k_wt<<<dim3(16, 64, 1), 256, 0, stream>>>(W2, gW2, D_, FF_, 0, 0);

    k_ln<<<MG, 256, 0, stream>>>(bA, bB, g_ln_g, g_ln_b, L_, 0, 1);          // xn (x_rec gather)
    gemm(stream, bB, gQKVO, bq, bk, bv, nullptr, nullptr, bQKV,
         MG, QKVS, D_, D_, 1, 0, 0, 0, 0, 0,
         QS, 1.0f, 0, 3, 0, 1);                                              // fused global QKV
    k_flash_mfma<<<B_ * H_ * NQT2_, 512, 0, stream>>>(bQKV, bB);             // ctx2 -> bB
    gemm(stream, bB, gQKVO + 3 * 262144, bo, nullptr, nullptr, x, nullptr, bA,
         MG, D_, D_, D_, 1, 0, 0, 0, 0, 0,
         1.0f, 1.0f, 0, 1, 1, 0);                                            // h f32 -> bA (res=x)
    k_ln<<<MG, 256, 0, stream>>>(bA, bB, f_ln_g, f_ln_b, MG, 0, 0);          // hn
    for (int c = 0; c < 2; c++) {    // global FFN, 2 chunks of 1024
        gemm(stream, bB, gW1 + (long long)c * 1024 * 512, b1 + c * 1024,
             nullptr, nullptr, nullptr, nullptr, bQKV,
             MG, 1024, D_, D_, 1, 0, 0, 0, 0, 0,
             1.0f, 1.0f, 1, 1, 0, 1);                                        // mid2 chunk (relu)
        gemm(stream, bQKV, gW2 + c * 1024, b2, nullptr, nullptr,
             (c == 0) ? bA : (float*)d_out, nullptr, d_out,
             MG, D_, 1024, FF_, 1, 0, 0, 0, 0, 0,
             1.0f, 1.0f, 0, (c == 0) ? 1 : 0, 1, 0);                         // out (in-place c=1)
    }
}

// Round 28
// 1326.496 us; speedup vs baseline: 1.0422x; 1.0380x over previous
//
#include <hip/hip_runtime.h>

#define B_   32
#define L_   796
#define D_   512
#define H_   8
#define HD_  64
#define FF_  2048
#define CS_  16
#define STR_ 13
#define NC_  61
#define NQT_ 13             // kv-tiles of 64
#define NQT2_ 7             // q-tiles of 128 rows (ceil(796/128))
#define MC_  976            // NC_*CS_ rows per batch (clip path)
#define QKVS 1536           // fused QKV row stride
#define QS   (0.125f * 1.44269504f)   // 1/sqrt(64) * log2(e)  -> exp2 softmax

typedef __attribute__((ext_vector_type(8))) short short8;
typedef __attribute__((ext_vector_type(4))) short short4v;
typedef __attribute__((ext_vector_type(4))) float f32x4;

__device__ __forceinline__ unsigned short f2bf(float x) {
    unsigned u = __float_as_uint(x);
    unsigned r = u + 0x7FFFu + ((u >> 16) & 1u);   // RNE
    return (unsigned short)(r >> 16);
}
__device__ __forceinline__ float bf2f(unsigned short h) {
    return __uint_as_float(((unsigned)h) << 16);
}
__device__ __forceinline__ float ex2(float x) {      // native v_exp_f32 (2^x)
    return __builtin_amdgcn_exp2f(x);
}
__device__ __forceinline__ void gload16(const unsigned short* g, unsigned short* l) {
    __builtin_amdgcn_global_load_lds(
        (const __attribute__((address_space(1))) void*)g,
        (__attribute__((address_space(3))) void*)l, 16, 0, 0);
}

// ---------------------------------------------------------------------------
// LayerNorm D=512, f32 in -> bf16 out.
// gather=0: direct rows; gather=1: x_rec remap; gather=2: clip build from x.
// ---------------------------------------------------------------------------
__global__ __launch_bounds__(256) void k_ln(const float* __restrict__ in,
                                            unsigned short* __restrict__ out,
                                            const float* __restrict__ gamma,
                                            const float* __restrict__ beta,
                                            int rows_per_batch, int gstride, int gather)
{
    __shared__ float red[8];
    long long row = blockIdx.x;
    int tid = threadIdx.x;
    int b;
    float v0, v1;
    if (gather == 2) {
        b = (int)(row / MC_);
        int rr = (int)(row % MC_);
        int n = rr >> 4, c = rr & 15;
        long long xb = (long long)b * L_ * D_;
        int d0 = tid, st0, sd0;
        if (d0 < 128) { st0 = n * STR_ + c; sd0 = d0; }
        else { int j = d0 - 128; st0 = n * STR_ + (j & 15); sd0 = 128 + ((j >> 4) << 4) + c; }
        v0 = in[xb + (long long)st0 * D_ + sd0];
        int j1 = tid + 128;                 // (tid+256)-128
        int st1 = n * STR_ + (j1 & 15), sd1 = 128 + ((j1 >> 4) << 4) + c;
        v1 = in[xb + (long long)st1 * D_ + sd1];
    } else {
        long long srow = row;
        if (gather == 1) {
            int p = (int)(row % L_);
            b = (int)(row / L_);
            int ci = p / STR_; if (ci > NC_ - 1) ci = NC_ - 1;
            srow = ((long long)b * NC_ + ci) * CS_ + (p - ci * STR_);
        } else {
            b = (int)(row / rows_per_batch);
        }
        const float* xr = in + srow * D_;
        v0 = xr[tid]; v1 = xr[tid + 256];
    }
    float s = v0 + v1;
#pragma unroll
    for (int off = 1; off < 64; off <<= 1) s += __shfl_xor(s, off);
    if ((tid & 63) == 0) red[tid >> 6] = s;
    __syncthreads();
    float mean = (red[0] + red[1] + red[2] + red[3]) * (1.0f / 512.0f);
    float d0 = v0 - mean, d1 = v1 - mean;
    float vv = d0 * d0 + d1 * d1;
#pragma unroll
    for (int off = 1; off < 64; off <<= 1) vv += __shfl_xor(vv, off);
    if ((tid & 63) == 0) red[4 + (tid >> 6)] = vv;
    __syncthreads();
    float var = (red[4] + red[5] + red[6] + red[7]) * (1.0f / 512.0f);
    float rstd = rsqrtf(var + 1e-6f);
    const float* g  = gamma + (long long)b * gstride;
    const float* bt = beta  + (long long)b * gstride;
    unsigned short* o = out + row * D_;
    o[tid]       = f2bf(d0 * rstd * g[tid]       + bt[tid]);
    o[tid + 256] = f2bf(d1 * rstd * g[tid + 256] + bt[tid + 256]);
}

// ---------------------------------------------------------------------------
// Weight transpose+convert: W f32 [K x N] (row stride rowStride) -> T bf16
// [N][K] (row stride tStride). grid (N/32, K/32, G).
// ---------------------------------------------------------------------------
__global__ __launch_bounds__(256) void k_wt(const float* __restrict__ W,
                                            unsigned short* __restrict__ T,
                                            int rowStride, int tStride,
                                            long long sWb, long long sTb)
{
    __shared__ float t[32][33];
    int z = blockIdx.z;
    const float* Wz = W + (long long)z * sWb;
    unsigned short* Tz = T + (long long)z * sTb;
    int n0 = blockIdx.x << 5, k0 = blockIdx.y << 5;
    int tx = threadIdx.x & 31, ty = threadIdx.x >> 5;
#pragma unroll
    for (int i = 0; i < 4; i++) {
        int k = ty + (i << 3);
        t[k][tx] = Wz[(long long)(k0 + k) * rowStride + n0 + tx];
    }
    __syncthreads();
#pragma unroll
    for (int i = 0; i < 4; i++) {
        int n = ty + (i << 3);
        Tz[(long long)(n0 + n) * tStride + k0 + tx] = f2bf(t[tx][n]);
    }
}

// Stacked transpose of up to 4 square 512x512 tensors x nb batches.
// z = tensor*nb + batch. dst: [batch][tensor*512 + n][512].
__global__ __launch_bounds__(256) void k_wt_stack(const float* __restrict__ Wa,
                                                  const float* __restrict__ Wb,
                                                  const float* __restrict__ Wc,
                                                  const float* __restrict__ Wd,
                                                  unsigned short* __restrict__ T,
                                                  int nb, int ntens, long long sWb)
{
    __shared__ float t[32][33];
    int z = blockIdx.z;
    int tt = z / nb, b = z % nb;
    const float* Wz = (tt == 0 ? Wa : tt == 1 ? Wb : tt == 2 ? Wc : Wd)
                      + (long long)b * sWb;
    unsigned short* Tz = T + ((long long)b * ntens + tt) * (512 * 512);
    int n0 = blockIdx.x << 5, k0 = blockIdx.y << 5;
    int tx = threadIdx.x & 31, ty = threadIdx.x >> 5;
#pragma unroll
    for (int i = 0; i < 4; i++) {
        int k = ty + (i << 3);
        t[k][tx] = Wz[(long long)(k0 + k) * 512 + n0 + tx];
    }
    __syncthreads();
#pragma unroll
    for (int i = 0; i < 4; i++) {
        int n = ty + (i << 3);
        Tz[(long long)(n0 + n) * 512 + k0 + tx] = f2bf(t[tx][n]);
    }
}

// ---------------------------------------------------------------------------
// bf16 MFMA GEMM — counted-vmcnt pipeline (round-12 skeleton), BK=32,
// 512 thr / 8 waves (2M x 4N, each wave 64x32 out) — round-21/23/25 proven.
// NOTE: no min-waves clause (r22: forcing 8 waves/EU spilled VGPR 80->32).
// Swizzle key (r>>1)&3 (conflict-free, r20-verified: 0 conflicts).
// ---------------------------------------------------------------------------
__global__ __launch_bounds__(512) void k_gemm_mfma(
    const unsigned short* __restrict__ A, const unsigned short* __restrict__ WT,
    const float* __restrict__ b0p, const float* __restrict__ b1p,
    const float* __restrict__ b2p,
    const float* res, const float* __restrict__ xg, void* Cout,
    int M, int N, int K, int ldwk, int NX, int NYd, int mode,
    long long sAb, long long sWb, long long sBb, long long sRb, long long sCb,
    float alpha, float alpha1, int relu, int biasmode, int resmode, int outbf16)
{
    __shared__ unsigned short lds[16384];      // 32 KB: 2 x (A 8KB + W 8KB)
    int tid = threadIdx.x;

    // ---- XCD-aware decode ----
    int bid = blockIdx.x;
    int xcd = bid & 7, inner = bid >> 3;
    int x = inner % NX, t = inner / NX;
    int y, z;
    if (mode == 0) { y = t % NYd; z = (t / NYd) * 8 + xcd; }
    else           { y = t * 8 + xcd; z = 0; }
    int row0 = y << 7, col0 = x << 7;
    if (row0 >= M) return;                 // padded row-tile (mode 1)

    const unsigned short* Ab = A + z * sAb;
    const unsigned short* Wb = WT + z * sWb;

    int w = tid >> 6, lane = tid & 63;
    int wr = (w >> 2) << 6;                // 0 / 64
    int wc = (w & 3) << 5;                 // 0 / 32 / 64 / 96
    int l15 = lane & 15, lg = lane >> 4;   // lg in 0..3 = K-slot of 32
    int lrow4 = lane >> 2, lslot = lane & 3;   // staging: 16 rows x 4 slots/wave

    f32x4 acc[4][2];
#pragma unroll
    for (int i = 0; i < 4; i++)
#pragma unroll
        for (int j = 0; j < 2; j++) acc[i][j] = (f32x4)0.f;

    const int nt = K >> 5;                     // BK = 32
    int srow = (w << 4) + lrow4;               // staging row (wave w: rows w*16..+15)
    int skey = (srow >> 1) & 3;

    // ---- prologue: stage tile 0 -> buf0, tile 1 -> buf1 ----
#pragma unroll
    for (int pt = 0; pt < 2; ++pt) {
        int k0 = pt << 5;
        unsigned short* sA = lds + (pt << 13);
        unsigned short* sW = sA + 4096;
        gload16(Ab + (long long)(row0 + srow) * K + k0 + ((lslot ^ skey) << 3),
                sA + ((w << 4) << 5));
        gload16(Wb + (long long)(col0 + srow) * ldwk + k0 + ((lslot ^ skey) << 3),
                sW + ((w << 4) << 5));
    }

    for (int kt = 0; kt < nt; ++kt) {
        // (1) counted wait: tile kt's 2 loads landed; tile kt+1's stay in flight
        if (kt + 1 < nt) asm volatile("s_waitcnt vmcnt(2)" ::: "memory");
        else             asm volatile("s_waitcnt vmcnt(0)" ::: "memory");
        __builtin_amdgcn_s_barrier();      // all waves' tile-kt loads landed

        unsigned short* lA = lds + ((kt & 1) << 13);
        unsigned short* lW = lA + 4096;

        // (2) ds_read fragments of current buffer (slot = lg ^ key)
        short8 af[4], bfr[2];
#pragma unroll
        for (int mf = 0; mf < 4; mf++) {
            int r = wr + (mf << 4) + l15;
            af[mf] = *(const short8*)(lA + (r << 5) + ((lg ^ ((r >> 1) & 3)) << 3));
        }
#pragma unroll
        for (int nf = 0; nf < 2; nf++) {
            int r = wc + (nf << 4) + l15;
            bfr[nf] = *(const short8*)(lW + (r << 5) + ((lg ^ ((r >> 1) & 3)) << 3));
        }

        // (3) own reads retired -> all-waves barrier (raw: no vmcnt drain!)
        asm volatile("s_waitcnt lgkmcnt(0)" ::: "memory");
        __builtin_amdgcn_s_barrier();

        // (4) stage tile kt+2 into the buffer just consumed (now safe)
        if (kt + 2 < nt) {
            int k0 = (kt + 2) << 5;
            gload16(Ab + (long long)(row0 + srow) * K + k0 + ((lslot ^ skey) << 3),
                    lA + ((w << 4) << 5));
            gload16(Wb + (long long)(col0 + srow) * ldwk + k0 + ((lslot ^ skey) << 3),
                    lW + ((w << 4) << 5));
        }

        // (5) register-only MFMA cluster
        __builtin_amdgcn_s_setprio(1);
#pragma unroll
        for (int mf = 0; mf < 4; mf++)
#pragma unroll
            for (int nf = 0; nf < 2; nf++)
                acc[mf][nf] = __builtin_amdgcn_mfma_f32_16x16x32_bf16(
                    af[mf], bfr[nf], acc[mf][nf], 0, 0, 0);
        __builtin_amdgcn_s_setprio(0);
    }

#pragma unroll
    for (int mf = 0; mf < 4; mf++) {
#pragma unroll
        for (int reg = 0; reg < 4; reg++) {
            int gr = row0 + wr + (mf << 4) + (lg << 2) + reg;
            if (gr >= M) continue;
#pragma unroll
            for (int nf = 0; nf < 2; nf++) {
                int gc = col0 + wc + (nf << 4) + l15;
                float v = acc[mf][nf][reg];
                if (biasmode == 1) v += b0p[z * sBb + gc];
                else if (biasmode == 3) {
                    const float* bp = gc < 512 ? b0p : (gc < 1024 ? b1p : b2p);
                    v += bp[z * sBb + (gc & 511)];
                }
                v *= (gc < 512) ? alpha : alpha1;
                if (relu) v = fmaxf(v, 0.f);
                if (resmode == 1) {
                    v += res[z * sRb + (long long)gr * N + gc];
                } else if (resmode == 2) {
                    int n = gr >> 4, c = gr & 15;
                    int st, sd;
                    if (gc < 128) { st = n * STR_ + c; sd = gc; }
                    else {
                        int jj = gc - 128;
                        st = n * STR_ + (jj & 15);
                        sd = 128 + ((jj >> 4) << 4) + c;
                    }
                    v += xg[((long long)z * L_ + st) * D_ + sd];
                }
                long long co = z * sCb + (long long)gr * N + gc;
                if (outbf16) ((unsigned short*)Cout)[co] = f2bf(v);
                else         ((float*)Cout)[co] = v;
            }
        }
    }
}

// ---------------------------------------------------------------------------
// Clip attention on fused QKV (stride QKVS, offsets 0/512/1024), exp2 softmax.
// Vectorized: one short4 load per tensor per thread; packed ushort4 ctx store.
// ---------------------------------------------------------------------------
__global__ __launch_bounds__(256) void k_clip_attn(const unsigned short* __restrict__ qkv,
                                                   unsigned short* __restrict__ ctx)
{
    __shared__ float qs[CS_][65], ks[CS_][65], vs[CS_][65], ps[CS_][17];
    int id = blockIdx.x;
    int h = id & (H_ - 1);
    int n = (id / H_) % NC_;
    int b = id / (H_ * NC_);
    long long base = (((long long)b * NC_ + n) * CS_) * QKVS + h * HD_;
    int tid = threadIdx.x;
    {
        int e = tid << 2;                  // 4 contiguous elems (same row)
        int r = e >> 6, c = e & 63;
        long long ro = base + (long long)r * QKVS + c;
        short4v qv = *(const short4v*)(qkv + ro);
        short4v kv = *(const short4v*)(qkv + ro + 512);
        short4v vv = *(const short4v*)(qkv + ro + 1024);
#pragma unroll
        for (int j = 0; j < 4; j++) {
            qs[r][c + j] = bf2f((unsigned short)qv[j]);
            ks[r][c + j] = bf2f((unsigned short)kv[j]);
            vs[r][c + j] = bf2f((unsigned short)vv[j]);
        }
    }
    __syncthreads();
    int qr = tid >> 4, kc = tid & 15;
    float s = 0.f;
#pragma unroll
    for (int d = 0; d < HD_; d++) s += qs[qr][d] * ks[kc][d];
    float m = s;
#pragma unroll
    for (int off = 1; off < 16; off <<= 1) m = fmaxf(m, __shfl_xor(m, off));
    float e = ex2(s - m);
    float sum = e;
#pragma unroll
    for (int off = 1; off < 16; off <<= 1) sum += __shfl_xor(sum, off);
    ps[qr][kc] = e / sum;
    __syncthreads();
    int dg = (tid & 15) * 4;
    float o0 = 0, o1 = 0, o2 = 0, o3 = 0;
#pragma unroll
    for (int kk = 0; kk < CS_; kk++) {
        float pp = ps[qr][kk];
        o0 += pp * vs[kk][dg + 0];
        o1 += pp * vs[kk][dg + 1];
        o2 += pp * vs[kk][dg + 2];
        o3 += pp * vs[kk][dg + 3];
    }
    long long ob = ((((long long)b * NC_ + n) * CS_) + qr) * D_ + h * HD_ + dg;
    short4v ov;
    ov[0] = (short)f2bf(o0); ov[1] = (short)f2bf(o1);
    ov[2] = (short)f2bf(o2); ov[3] = (short)f2bf(o3);
    *(short4v*)(ctx + ob) = ov;
}

// ---------------------------------------------------------------------------
// Global flash attention (MFMA, exp2 softmax) on fused QKV buffer.
// 512 thr / 8 waves, 128-row q-tile, K/V double-buffered, 1 barrier/tile
// (r27 pipeline). NEW (T12 core): SWAPPED QK^T — mfma(K,Q) gives
// S[token][qrow] with qrow = l15, so each lane owns one q-row:
//   * row max/sum: in-lane over 16 + 2 shfl_xor(16,32)  (was 4 rounds x 4)
//   * m, l are SCALARS per lane (qrow = l15)            (was [4], -12 VGPR)
//   * P values token-contiguous: 4 packed ds_write_b64  (was 16 b16 writes)
// Fragment loads identical (A/B fragments share lane mapping); PV unchanged
// (P lands in the same [row][swizzled-token] layout its A-read expects).
// oacc rows are qrow=(lg<<2)+r -> rescale / 1/l fetched via __shfl from
// lane (lg<<2)+r. LDS 48KB; mask only last kv-tile; defer-max (T13);
// XCD swizzle h = bid&7.
// ---------------------------------------------------------------------------
__global__ __launch_bounds__(512) void k_flash_mfma(
    const unsigned short* __restrict__ qkv,
    unsigned short* __restrict__ out)
{
    __shared__ unsigned short sh[24576];   // 48KB
    unsigned short* lQ  = sh;              // 128x64 Q tile (dead after qf load)
    unsigned short* lKb = sh + 8192;       // K double buffer (2 x 64x64)
    unsigned short* lVb = sh + 16384;      // V double buffer (2 x 64x64, transposed)
    int bid = blockIdx.x;
    int h  = bid & 7;
    int inner = bid >> 3;
    int qt = inner % NQT2_;
    int b  = inner / NQT2_;
    int tid = threadIdx.x;
    int q0 = qt * 128;
    long long base = (long long)b * L_ * QKVS + h * HD_;

    int w = tid >> 6, lane = tid & 63;     // w in 0..7
    int l15 = lane & 15, lg = lane >> 4;
    int lrow = lane >> 3, lslot = lane & 7;
    int srow = lane;                       // V staging: token 0..63
    int sd0  = w << 3;                     // V staging: d-group of 8 (8 waves)

    // ---- prologue: stage Q; issue K(0) gload; V(0) -> regs ----
#pragma unroll
    for (int i = 0; i < 2; i++) {
        int cb = (w << 4) + (i << 3);
        int rr = cb + lrow;
        gload16(qkv + base + (long long)(q0 + rr) * QKVS + ((lslot ^ (rr & 7)) << 3),
                lQ + (cb << 6));
    }
    {
        int rr = (w << 3) + lrow;
        gload16(qkv + base + 512 + (long long)rr * QKVS + ((lslot ^ (rr & 7)) << 3),
                lKb + ((w << 3) << 6));
    }
    short8 vreg = *(const short8*)(qkv + base + 1024 + (long long)srow * QKVS + sd0);
    __syncthreads();                       // Q + K(0) in LDS (vmcnt drained)

    int qrow = (w << 4) + l15;
    short8 qf[2];
#pragma unroll
    for (int ks = 0; ks < 2; ks++) {
        int slot = (ks << 2) + lg;
        qf[ks] = *(const short8*)(lQ + qrow * 64 + ((slot ^ (qrow & 7)) << 3));
    }
    // each wave's Q reads retired before it crosses the first loop barrier;
    // its P region (below) overlays exactly its own Q rows -> alias safe.
    asm volatile("s_waitcnt lgkmcnt(0)" ::: "memory");
    unsigned short* lPw = lQ + (w << 10);  // per-wave 16x64 P scratch

    float m = -1e30f, l = 0.f;             // softmax state for qrow = l15
    f32x4 oacc[4];
#pragma unroll
    for (int nf = 0; nf < 4; nf++) oacc[nf] = (f32x4)0.f;

    int ts = srow >> 3, t7 = srow & 7;
    int pkey = l15 & 7;                    // P-row swizzle key (row = l15)
    for (int kt = 0; kt < NQT_; kt++) {    // 13 kv-tiles of 64
        int k0 = kt * 64;
        unsigned short* lK = lKb + ((kt & 1) << 12);
        unsigned short* lV = lVb + ((kt & 1) << 12);
        // ---- ds_write V(kt) from regs (transposed + swizzled) ----
#pragma unroll
        for (int i = 0; i < 8; i++) {
            int d = sd0 + i;
            lV[d * 64 + ((ts ^ (d & 7)) << 3) + t7] = (unsigned short)vreg[i];
        }
        __syncthreads();   // drains vmcnt+lgkm: K(kt) in LDS, V(kt) writes visible

        // ---- swapped QK^T: acc = S[token][qrow], qrow = l15 ----
        f32x4 acc[4];
#pragma unroll
        for (int nf = 0; nf < 4; nf++) {
            acc[nf] = (f32x4)0.f;
            int tok = (nf << 4) + l15;
            int key = tok & 7;
#pragma unroll
            for (int ks = 0; ks < 2; ks++) {
                int slot = (ks << 2) + lg;
                short8 kf = *(const short8*)(lK + tok * 64 + ((slot ^ key) << 3));
                acc[nf] = __builtin_amdgcn_mfma_f32_16x16x32_bf16(kf, qf[ks], acc[nf], 0, 0, 0);
            }
        }
        // ---- issue next-tile loads into the OTHER buffers (latency hides
        //      under softmax + PV; consumed only after the next barrier) ----
        if (kt + 1 < NQT_) {
            int k0n = (kt + 1) << 6;
            int rr = (w << 3) + lrow;
            gload16(qkv + base + 512 + (long long)(k0n + rr) * QKVS + ((lslot ^ (rr & 7)) << 3),
                    lKb + (((kt + 1) & 1) << 12) + ((w << 3) << 6));
            int grn = k0n + srow;
            vreg = (short8)0;
            if (grn < L_)
                vreg = *(const short8*)(qkv + base + 1024 + (long long)grn * QKVS + sd0);
        }
        // ---- mask (last kv-tile only; token = k0 + nf*16 + lg*4 + r) ----
        if (kt == NQT_ - 1) {
#pragma unroll
            for (int nf = 0; nf < 4; nf++) {
                int tb = k0 + (nf << 4) + (lg << 2);
#pragma unroll
                for (int r = 0; r < 4; r++)
                    if (tb + r >= L_) acc[nf][r] = -1e30f;
            }
        }
        // ---- row max: in-lane 16 + 2 cross-lane rounds ----
        float rm = -1e30f;
#pragma unroll
        for (int nf = 0; nf < 4; nf++) {
#pragma unroll
            for (int r = 0; r < 4; r++) rm = fmaxf(rm, acc[nf][r]);
        }
        rm = fmaxf(rm, __shfl_xor(rm, 16));
        rm = fmaxf(rm, __shfl_xor(rm, 32));
        // ---- defer-max (T13): rescale only if some row grew by >8 (log2) ----
        if (__ballot(rm > m + 8.0f)) {
            float mn = fmaxf(m, rm);
            float sc = ex2(m - mn);
            m = mn;
            l *= sc;
            float scr[4];
#pragma unroll
            for (int r = 0; r < 4; r++) scr[r] = __shfl(sc, (lg << 2) + r);
#pragma unroll
            for (int nf = 0; nf < 4; nf++)
#pragma unroll
                for (int r = 0; r < 4; r++) oacc[nf][r] *= scr[r];
        }
        // ---- P = exp2(S-m): 4 packed b64 writes, in-lane sum ----
        float ls = 0.f;
#pragma unroll
        for (int nf = 0; nf < 4; nf++) {
            short4v pk;
#pragma unroll
            for (int r = 0; r < 4; r++) {
                float p = ex2(acc[nf][r] - m);
                ls += p;
                pk[r] = (short)f2bf(p);
            }
            int s8 = (nf << 1) + (lg >> 1);        // token byte-slot of 8
            *(short4v*)(lPw + l15 * 64 + ((s8 ^ pkey) << 3) + ((lg & 1) << 2)) = pk;
        }
        ls += __shfl_xor(ls, 16);
        ls += __shfl_xor(ls, 32);
        l += ls;
        // ---- PV (wave-private lPw: in-order DS, no barrier needed) ----
#pragma unroll
        for (int ks = 0; ks < 2; ks++) {
            int slot = (ks << 2) + lg;
            short8 pa = *(const short8*)(lPw + l15 * 64 + ((slot ^ pkey) << 3));
#pragma unroll
            for (int nf = 0; nf < 4; nf++) {
                int d = (nf << 4) + l15;
                short8 vb = *(const short8*)(lV + d * 64 + ((slot ^ (d & 7)) << 3));
                oacc[nf] = __builtin_amdgcn_mfma_f32_16x16x32_bf16(pa, vb, oacc[nf], 0, 0, 0);
            }
        }
    }
    long long obase = (long long)b * L_ * D_ + h * HD_;
#pragma unroll
    for (int r = 0; r < 4; r++) {
        int gr = q0 + (w << 4) + (lg << 2) + r;
        if (gr >= L_) continue;
        float inv = 1.f / __shfl(l, (lg << 2) + r);
        long long ob = obase + (long long)gr * D_;
#pragma unroll
        for (int nf = 0; nf < 4; nf++)
            out[ob + (nf << 4) + l15] = f2bf(oacc[nf][r] * inv);
    }
}

// ---------------------------------------------------------------------------
// gemm launcher: 1D grid + XCD swizzle, 512 threads. mode 0 iff G>1.
// ---------------------------------------------------------------------------
static inline void gemm(hipStream_t st, const unsigned short* A, const unsigned short* WTp,
                        const float* b0, const float* b1, const float* b2,
                        const float* res, const float* xg, void* C,
                        int M, int N, int K, int ldwk, int G,
                        long long sAb, long long sWb, long long sBb,
                        long long sRb, long long sCb,
                        float alpha, float alpha1, int relu, int biasmode,
                        int resmode, int outbf16)
{
    int NX = N / 128;
    int NY = (M + 127) >> 7;
    int mode = (G > 1) ? 0 : 1;
    int NYp = mode ? ((NY + 7) & ~7) : NY;
    int nblk = mode ? (NYp * NX) : (G * NY * NX);
    k_gemm_mfma<<<nblk, 512, 0, st>>>(A, WTp, b0, b1, b2, res, xg, C,
                                      M, N, K, ldwk, NX, NY, mode,
                                      sAb, sWb, sBb, sRb, sCb,
                                      alpha, alpha1, relu, biasmode, resmode, outbf16);
}

extern "C" void kernel_launch(void* const* d_in, const int* in_sizes, int n_in,
                              void* d_out, int out_size, void* d_ws, size_t ws_size,
                              hipStream_t stream)
{
    (void)in_sizes; (void)n_in; (void)out_size; (void)ws_size;
    const float* x      = (const float*)d_in[0];
    const float* g_ln_g = (const float*)d_in[2];
    const float* g_ln_b = (const float*)d_in[3];
    const float* Wq = (const float*)d_in[4];
    const float* Wk = (const float*)d_in[5];
    const float* Wv = (const float*)d_in[6];
    const float* Wo = (const float*)d_in[7];
    const float* bq = (const float*)d_in[8];
    const float* bk = (const float*)d_in[9];
    const float* bv = (const float*)d_in[10];
    const float* bo = (const float*)d_in[11];
    const float* f_ln_g = (const float*)d_in[12];
    const float* f_ln_b = (const float*)d_in[13];
    const float* W1 = (const float*)d_in[14];
    const float* b1 = (const float*)d_in[15];
    const float* W2 = (const float*)d_in[16];
    const float* b2 = (const float*)d_in[17];
    const float* c_ln_g = (const float*)d_in[18];
    const float* c_ln_b = (const float*)d_in[19];
    const float* cWq = (const float*)d_in[20];
    const float* cWk = (const float*)d_in[21];
    const float* cWv = (const float*)d_in[22];
    const float* cWo = (const float*)d_in[23];
    const float* cbq = (const float*)d_in[24];
    const float* cbk = (const float*)d_in[25];
    const float* cbv = (const float*)d_in[26];
    const float* cbo = (const float*)d_in[27];
    const float* cf_ln_g = (const float*)d_in[28];
    const float* cf_ln_b = (const float*)d_in[29];
    const float* cW1 = (const float*)d_in[30];
    const float* cb1 = (const float*)d_in[31];
    const float* cW2 = (const float*)d_in[32];
    const float* cb2 = (const float*)d_in[33];

    // ---- workspace layout (236 MB) ----
    char* wsb = (char*)d_ws;
    float*          bA   = (float*)wsb;                              // 64MB f32: hcl -> clips_out -> h
    unsigned short* bB   = (unsigned short*)(wsb + (64ll  << 20));   // 32MB bf16 activations
    unsigned short* bQKV = (unsigned short*)(wsb + (96ll  << 20));   // 92MB: fused qkv / fmid chunks
    unsigned short* wT   = (unsigned short*)(wsb + (188ll << 20));   // 48MB: weight transposes

    const long long sA   = (long long)MC_ * D_;
    const long long sQKV = (long long)MC_ * QKVS;
    const long long sWW  = (long long)D_ * D_;
    const int MG = B_ * L_;

    // ================= clip path =================
    k_ln<<<B_ * MC_, 256, 0, stream>>>(x, bB, c_ln_g, c_ln_b, MC_, D_, 2);   // cn (fused gather)
    k_wt_stack<<<dim3(16, 16, 3 * B_), 256, 0, stream>>>(cWq, cWk, cWv, nullptr,
                                                         wT, B_, 3, sWW);
    gemm(stream, bB, wT, cbq, cbk, cbv, nullptr, nullptr, bQKV,
         MC_, QKVS, D_, D_, B_, sA, 3 * sWW, D_, 0, sQKV,
         QS, 1.0f, 0, 3, 0, 1);                                              // fused clip QKV
    k_clip_attn<<<B_ * NC_ * H_, 256, 0, stream>>>(bQKV, bB);                // ctx -> bB
    k_wt<<<dim3(16, 16, B_), 256, 0, stream>>>(cWo, wT, D_, D_, sWW, sWW);
    gemm(stream, bB, wT, cbo, nullptr, nullptr, nullptr, x, bA,
         MC_, D_, D_, D_, B_, sA, sWW, D_, 0, sA,
         1.0f, 1.0f, 0, 1, 2, 0);                                            // hcl f32 -> bA
    k_ln<<<B_ * MC_, 256, 0, stream>>>(bA, bB, cf_ln_g, cf_ln_b, MC_, D_, 0); // fn
    for (int c = 0; c < 2; c++) {   // clip FFN, 2 chunks of 1024
        k_wt<<<dim3(32, 16, B_), 256, 0, stream>>>(cW1 + c * 1024, wT, FF_, D_,
                                                   (long long)D_ * FF_, 1024ll * D_);
        gemm(stream, bB, wT, cb1 + c * 1024, nullptr, nullptr, nullptr, nullptr, bQKV,
             MC_, 1024, D_, D_, B_, sA, 1024ll * D_, FF_, 0, (long long)MC_ * 1024,
             1.0f, 1.0f, 1, 1, 0, 1);                                        // fmid chunk (relu)
        k_wt<<<dim3(16, 32, B_), 256, 0, stream>>>(cW2 + (long long)c * 1024 * D_, wT,
                                                   D_, 1024, (long long)FF_ * D_,
                                                   (long long)D_ * 1024);
        gemm(stream, bQKV, wT, cb2, nullptr, nullptr, bA, nullptr, bA,
             MC_, D_, 1024, 1024, B_, (long long)MC_ * 1024, (long long)D_ * 1024,
             D_, sA, sA, 1.0f, 1.0f, 0, (c == 0) ? 1 : 0, 1, 0);             // clips_out in-place bA
    }

    // ================= global path =================
    unsigned short* gQKVO = wT;                    // [2048][512]
    unsigned short* gW1   = wT + 4 * 262144;       // [2048][512]
    unsigned short* gW2   = wT + 8 * 262144;       // [512][2048]
    k_wt_stack<<<dim3(16, 16, 4), 256, 0, stream>>>(Wq, Wk, Wv, Wo, gQKVO, 1, 4, 0);
    k_wt<<<dim3(64, 16, 1), 256, 0, stream>>>(W1, gW1, FF_, D_, 0, 0);
    k_wt<<<dim3(16, 64, 1), 256, 0, stream>>>(W2, gW2, D_, FF_, 0, 0);

    k_ln<<<MG, 256, 0, stream>>>(bA, bB, g_ln_g, g_ln_b, L_, 0, 1);          // xn (x_rec gather)
    gemm(stream, bB, gQKVO, bq, bk, bv, nullptr, nullptr, bQKV,
         MG, QKVS, D_, D_, 1, 0, 0, 0, 0, 0,
         QS, 1.0f, 0, 3, 0, 1);                                              // fused global QKV
    k_flash_mfma<<<B_ * H_ * NQT2_, 512, 0, stream>>>(bQKV, bB);             // ctx2 -> bB
    gemm(stream, bB, gQKVO + 3 * 262144, bo, nullptr, nullptr, x, nullptr, bA,
         MG, D_, D_, D_, 1, 0, 0, 0, 0, 0,
         1.0f, 1.0f, 0, 1, 1, 0);                                            // h f32 -> bA (res=x)
    k_ln<<<MG, 256, 0, stream>>>(bA, bB, f_ln_g, f_ln_b, MG, 0, 0);          // hn
    for (int c = 0; c < 2; c++) {    // global FFN, 2 chunks of 1024
        gemm(stream, bB, gW1 + (long long)c * 1024 * 512, b1 + c * 1024,
             nullptr, nullptr, nullptr, nullptr, bQKV,
             MG, 1024, D_, D_, 1, 0, 0, 0, 0, 0,
             1.0f, 1.0f, 1, 1, 0, 1);                                        // mid2 chunk (relu)
        gemm(stream, bQKV, gW2 + c * 1024, b2, nullptr, nullptr,
             (c == 0) ? bA : (float*)d_out, nullptr, d_out,
             MG, D_, 1024, FF_, 1, 0, 0, 0, 0, 0,
             1.0f, 1.0f, 0, (c == 0) ? 1 : 0, 1, 0);                         // out (in-place c=1)
    }
}